// Round 9
// baseline (139.058 us; speedup 1.0000x reference)
//
#include <hip/hip_runtime.h>
#include <stdint.h>

#define H_ 152
#define W_ 152
#define A_ 9
#define HW_ (H_ * W_)          // 23104
#define N_ (HW_ * A_)          // 207936
#define B_ 8
#define PRE_TOP 6000
#define POST_TOP 300
#define NBUCK 4096
#define NFINE 32768
#define CAND_CAP 8192
#define NMS_TH 0.7f
#define CNT_STRIDE 32          // pad per-batch counters to 128 B
#define RTILE 512
#define GS 128                 // NMS group size

// workspace byte offsets
#define OFF_HIST    0                                   // 8*4096*4 = 131072
#define OFF_SSUF    131072                              // (unused, kept for layout)
#define OFF_CNT     262144                              // 8*32*4   = 1024
#define OFF_CAND    263168                              // 8*8192*8 = 524288  (reused as S16 u16[32768]/batch)
#define OFF_GROUP   787456                              // 8*8192*8 = 524288
#define OFF_BOXES   1311744                             // 8*6000*16= 768000
#define OFF_BALL    2079744                             // 8*207936*16 = 26615808
#define WS_NEED     (2079744ull + 26615808ull)          // 28695552

// ---------- helpers ----------

__device__ __forceinline__ unsigned fkey(float f) {
    unsigned u = __float_as_uint(f);
    return (u & 0x80000000u) ? ~u : (u | 0x80000000u);   // monotonic float->u32
}

__device__ __forceinline__ bool sup_test(float ax1, float ay1, float ax2, float ay2, float aar,
                                         float bx1, float by1, float bx2, float by2, float bar) {
    float xx1 = fmaxf(ax1, bx1);
    float yy1 = fmaxf(ay1, by1);
    float xx2 = fminf(ax2, bx2);
    float yy2 = fminf(ay2, by2);
    float iw = fmaxf(xx2 - xx1 + 1.0f, 0.0f);
    float ih = fmaxf(yy2 - yy1 + 1.0f, 0.0f);
    float inter = __fmul_rn(iw, ih);
    float iou = inter / (aar + bar - inter);
    return iou > NMS_TH;
}

// decode one box, op-order identical to reference/numpy
__device__ __forceinline__ float4 decode_box(float an0, float an1, float an2, float an3,
                                             float sx, float sy,
                                             float dx, float dy, float dw, float dh,
                                             float wmax, float hmax) {
    float ax1 = an0 + sx;
    float ay1 = an1 + sy;
    float ax2 = an2 + sx;
    float ay2 = an3 + sy;
    float ww = ax2 - ax1 + 1.0f;
    float hh = ay2 - ay1 + 1.0f;
    float ctx = ax1 + 0.5f * ww;
    float cty = ay1 + 0.5f * hh;
    float pcx = __fadd_rn(__fmul_rn(dx, ww), ctx);   // no FMA contraction (match np)
    float pcy = __fadd_rn(__fmul_rn(dy, hh), cty);
    float pw = __fmul_rn(expf(dw), ww);
    float ph = __fmul_rn(expf(dh), hh);
    float x1 = pcx - 0.5f * pw;
    float y1 = pcy - 0.5f * ph;
    float x2 = pcx + 0.5f * pw;
    float y2 = pcy + 0.5f * ph;
    x1 = fminf(fmaxf(x1, 0.0f), wmax);
    y1 = fminf(fmaxf(y1, 0.0f), hmax);
    x2 = fminf(fmaxf(x2, 0.0f), wmax);
    y2 = fminf(fmaxf(y2, 0.0f), hmax);
    return make_float4(x1, y1, x2, y2);
}

// ---------- kernels ----------

// zero two regions in one launch
__global__ void zero2_k(unsigned* __restrict__ base, unsigned* __restrict__ p2) {
    const int n1 = 263168 / 4;      // hist + (ssuf pad) + cnt
    const int n2 = 768000 / 4;      // boxes (defensive)
    int i = blockIdx.x * blockDim.x + threadIdx.x;
    int st = gridDim.x * blockDim.x;
    for (int k = i; k < n1 + n2; k += st) {
        if (k < n1) base[k] = 0u;
        else p2[k - n1] = 0u;
    }
}

// decode+clip ALL boxes, coalesced: boxesAll[b][a*HW+pix]
__global__ void decode_all_k(const float* __restrict__ deltas,
                             const float* __restrict__ anchors,
                             const float* __restrict__ im_info,
                             float4* __restrict__ ball) {
    int ba = blockIdx.y;           // 0..71
    int b = ba / A_, a = ba - (ba / A_) * A_;
    int pix = blockIdx.x * blockDim.x + threadIdx.x;
    if (pix >= HW_) return;
    const float* db = deltas + ((size_t)b * 36 + 4 * a) * HW_;
    float dx = db[pix];
    float dy = db[pix + HW_];
    float dw = db[pix + 2 * HW_];
    float dh = db[pix + 3 * HW_];
    float an0 = anchors[a * 4 + 0];
    float an1 = anchors[a * 4 + 1];
    float an2 = anchors[a * 4 + 2];
    float an3 = anchors[a * 4 + 3];
    float hmax = im_info[b * 3 + 0] - 1.0f;
    float wmax = im_info[b * 3 + 1] - 1.0f;
    int w = pix % W_, h = pix / W_;
    float sx = (float)(w * 16), sy = (float)(h * 16);
    ball[(size_t)b * N_ + a * HW_ + pix] =
        decode_box(an0, an1, an2, an3, sx, sy, dx, dy, dw, dh, wmax, hmax);
}

__global__ void hist_k(const float* __restrict__ scores, unsigned* __restrict__ hist) {
    __shared__ unsigned lh[NBUCK];
    int b = blockIdx.y;
    for (int i = threadIdx.x; i < NBUCK; i += blockDim.x) lh[i] = 0;
    __syncthreads();
    const float4* sb = (const float4*)(scores + ((size_t)b * 18 + A_) * HW_);
    const int N4 = N_ / 4;                      // 51984
    int stride = gridDim.x * blockDim.x;
    for (int e = blockIdx.x * blockDim.x + threadIdx.x; e < N4; e += stride) {
        float4 v = sb[e];
        atomicAdd(&lh[fkey(v.x) >> 20], 1u);
        atomicAdd(&lh[fkey(v.y) >> 20], 1u);
        atomicAdd(&lh[fkey(v.z) >> 20], 1u);
        atomicAdd(&lh[fkey(v.w) >> 20], 1u);
    }
    __syncthreads();
    for (int i = threadIdx.x; i < NBUCK; i += blockDim.x) {
        unsigned v = lh[i];
        if (v) atomicAdd(&hist[b * NBUCK + i], v);
    }
}

// suffix scan from top bucket; finds the coarse threshold bucket only.
__global__ void scan_k(const unsigned* __restrict__ hist, unsigned* __restrict__ bucketT) {
    __shared__ unsigned ps[1024];
    int b = blockIdx.x, t = threadIdx.x;
    const unsigned* hb = hist + b * NBUCK;
    unsigned c0 = hb[4095 - (4 * t + 0)];
    unsigned c1 = hb[4095 - (4 * t + 1)];
    unsigned c2 = hb[4095 - (4 * t + 2)];
    unsigned c3 = hb[4095 - (4 * t + 3)];
    unsigned local = c0 + c1 + c2 + c3;
    ps[t] = local;
    __syncthreads();
    for (int off = 1; off < 1024; off <<= 1) {
        unsigned v = (t >= off) ? ps[t - off] : 0u;
        __syncthreads();
        ps[t] += v;
        __syncthreads();
    }
    unsigned incl = ps[t], excl = incl - local;
    if (excl < PRE_TOP && incl >= PRE_TOP) {
        unsigned cum = excl;
        unsigned cc[4] = {c0, c1, c2, c3};
#pragma unroll
        for (int k = 0; k < 4; ++k) {
            cum += cc[k];
            if (cum >= PRE_TOP) { bucketT[b] = (unsigned)(4095 - (4 * t + k)); break; }
        }
    }
    if (t == 1023 && ps[1023] < PRE_TOP) bucketT[b] = 0;  // safety: include everything
}

__global__ void compact_k(const float* __restrict__ scores, const unsigned* __restrict__ bucketT,
                          unsigned* __restrict__ cnt, uint2* __restrict__ cand) {
    __shared__ unsigned wtot[4], wbase[4];
    __shared__ unsigned blkbase;
    int b = blockIdx.y;
    const float4* sb = (const float4*)(scores + ((size_t)b * 18 + A_) * HW_);
    unsigned T = bucketT[b];
    int lane = threadIdx.x & 63;
    int wid = threadIdx.x >> 6;
    const int N4 = N_ / 4;
    int stride = gridDim.x * blockDim.x;
    int niters = (N4 + stride - 1) / stride;
    unsigned long long lower = (lane == 63) ? 0x7fffffffffffffffull
                                            : ((1ull << lane) - 1ull);
    for (int it = 0; it < niters; ++it) {
        int e = it * stride + blockIdx.x * (int)blockDim.x + (int)threadIdx.x;
        bool p0 = false, p1 = false, p2 = false, p3 = false;
        unsigned k0 = 0, k1 = 0, k2 = 0, k3 = 0;
        if (e < N4) {
            float4 v = sb[e];
            k0 = fkey(v.x); k1 = fkey(v.y); k2 = fkey(v.z); k3 = fkey(v.w);
            p0 = (k0 >> 20) >= T; p1 = (k1 >> 20) >= T;
            p2 = (k2 >> 20) >= T; p3 = (k3 >> 20) >= T;
        }
        unsigned long long m0 = __ballot(p0), m1 = __ballot(p1);
        unsigned long long m2 = __ballot(p2), m3 = __ballot(p3);
        unsigned t0 = (unsigned)__popcll(m0), t1 = (unsigned)__popcll(m1);
        unsigned t2 = (unsigned)__popcll(m2), t3 = (unsigned)__popcll(m3);
        unsigned wtotal = t0 + t1 + t2 + t3;
        if (lane == 0) wtot[wid] = wtotal;
        __syncthreads();
        if (threadIdx.x == 0) {
            unsigned s0 = wtot[0], s1 = wtot[1], s2 = wtot[2], s3 = wtot[3];
            unsigned tot = s0 + s1 + s2 + s3;
            blkbase = tot ? atomicAdd(&cnt[b * CNT_STRIDE], tot) : 0u;
            wbase[0] = 0; wbase[1] = s0; wbase[2] = s0 + s1; wbase[3] = s0 + s1 + s2;
        }
        __syncthreads();
        if (wtotal) {
            unsigned base = blkbase + wbase[wid];
            unsigned o0 = base + (unsigned)__popcll(m0 & lower);
            unsigned o1 = base + t0 + (unsigned)__popcll(m1 & lower);
            unsigned o2 = base + t0 + t1 + (unsigned)__popcll(m2 & lower);
            unsigned o3 = base + t0 + t1 + t2 + (unsigned)__popcll(m3 & lower);
            uint2* cb = cand + (size_t)b * CAND_CAP;
            int e4 = e * 4;
            if (p0 && o0 < CAND_CAP) {
                int a = (e4 + 0) / HW_, pix = (e4 + 0) - a * HW_;
                cb[o0] = make_uint2(k0, (unsigned)(pix * A_ + a));
            }
            if (p1 && o1 < CAND_CAP) {
                int a = (e4 + 1) / HW_, pix = (e4 + 1) - a * HW_;
                cb[o1] = make_uint2(k1, (unsigned)(pix * A_ + a));
            }
            if (p2 && o2 < CAND_CAP) {
                int a = (e4 + 2) / HW_, pix = (e4 + 2) - a * HW_;
                cb[o2] = make_uint2(k2, (unsigned)(pix * A_ + a));
            }
            if (p3 && o3 < CAND_CAP) {
                int a = (e4 + 3) / HW_, pix = (e4 + 3) - a * HW_;
                cb[o3] = make_uint2(k3, (unsigned)(pix * A_ + a));
            }
        }
    }
}

// Fine (16-bit) counting sort of candidates: histogram -> suffix scan -> scatter.
// Afterwards writes per-fine-bucket END offsets (u16) over the dead cand slice.
__global__ void __launch_bounds__(1024) finesort_k(const unsigned* __restrict__ cnt,
                                                   uint2* __restrict__ cand,
                                                   unsigned long long* __restrict__ grouped) {
    __shared__ unsigned lh[NFINE];     // 128 KiB
    __shared__ unsigned ps[1024];
    int b = blockIdx.x, t = threadIdx.x;
    int M = min((int)cnt[b * CNT_STRIDE], CAND_CAP);
    uint2* cb = cand + (size_t)b * CAND_CAP;
    unsigned long long* g = grouped + (size_t)b * CAND_CAP;
    for (int i = t; i < NFINE; i += 1024) lh[i] = 0u;
    __syncthreads();
    for (int i = t; i < M; i += 1024) {
        unsigned key16 = cb[i].x >> 16;
        unsigned f = (key16 >= 32768u) ? (key16 - 32768u) : 0u;
        atomicAdd(&lh[f], 1u);
    }
    __syncthreads();
    unsigned c[32];
    unsigned local = 0;
#pragma unroll
    for (int k = 0; k < 32; ++k) { c[k] = lh[32767 - (32 * t + k)]; local += c[k]; }
    ps[t] = local;
    __syncthreads();
    for (int off = 1; off < 1024; off <<= 1) {
        unsigned v = (t >= off) ? ps[t - off] : 0u;
        __syncthreads();
        ps[t] += v;
        __syncthreads();
    }
    unsigned run = ps[t] - local;       // elements in all higher-f chunks
    __syncthreads();
#pragma unroll
    for (int k = 0; k < 32; ++k) {      // overwrite lh with S_start[f]
        lh[32767 - (32 * t + k)] = run;
        run += c[k];
    }
    __syncthreads();
    for (int i = t; i < M; i += 1024) {
        uint2 cd = cb[i];
        unsigned key16 = cd.x >> 16;
        unsigned f = (key16 >= 32768u) ? (key16 - 32768u) : 0u;
        unsigned pos = atomicAdd(&lh[f], 1u);
        if (pos < CAND_CAP)
            g[pos] = ((unsigned long long)cd.x << 32) | (unsigned)(~cd.y);
    }
    __syncthreads();
    ushort* S16 = (ushort*)cb;          // cand slice is dead; 32768*2B = 64 KiB fits exactly
    for (int i = t; i < NFINE; i += 1024)
        S16[i] = (ushort)min(lh[i], 65535u);
}

// rank candidate within its FINE bucket (count greater composites), then place its
// (pre-decoded) box into boxes[b][rank].
__global__ void __launch_bounds__(256) rank_k(const unsigned* __restrict__ cnt,
                                              const unsigned long long* __restrict__ grouped,
                                              const ushort* __restrict__ S16all,
                                              const float* __restrict__ deltas,
                                              const float* __restrict__ anchors,
                                              const float* __restrict__ im_info,
                                              const float4* __restrict__ ball,
                                              float4* __restrict__ boxes) {
    __shared__ unsigned long long tile[RTILE];
    __shared__ int s_rs, s_re;
    int b = blockIdx.y, t = threadIdx.x;
    int M = min((int)cnt[b * CNT_STRIDE], CAND_CAP);
    int c0 = blockIdx.x * 256;
    if (c0 >= M) return;
    const unsigned long long* g = grouped + (size_t)b * CAND_CAP;
    const ushort* S16 = S16all + (size_t)b * NFINE;
    int i = c0 + t;
    bool valid = i < M;
    unsigned long long comp = valid ? g[i] : 0ull;

    unsigned n = valid ? ~(unsigned)comp : 0u;
    int a = (int)(n % A_);
    int pix = (int)(n / A_);

    float4 pre = make_float4(0.f, 0.f, 0.f, 0.f);
    float dx = 0.f, dy = 0.f, dw = 0.f, dh = 0.f;
    float an0 = 0.f, an1 = 0.f, an2 = 0.f, an3 = 0.f, hmax = 0.f, wmax = 0.f;
    if (ball) {
        if (valid) pre = ball[(size_t)b * N_ + a * HW_ + pix];
    } else if (valid) {
        const float* db = deltas + (size_t)b * 36 * HW_;
        int didx = (4 * a) * HW_ + pix;
        dx = db[didx];
        dy = db[didx + HW_];
        dw = db[didx + 2 * HW_];
        dh = db[didx + 3 * HW_];
        an0 = anchors[a * 4 + 0];
        an1 = anchors[a * 4 + 1];
        an2 = anchors[a * 4 + 2];
        an3 = anchors[a * 4 + 3];
        hmax = im_info[b * 3 + 0] - 1.0f;
        wmax = im_info[b * 3 + 1] - 1.0f;
    }

    unsigned key16 = (unsigned)(comp >> 48);
    int f = (key16 >= 32768u) ? (int)(key16 - 32768u) : 0;
    int bs = 0, be = 0;
    if (valid) {
        bs = (f < 32767) ? min((int)S16[f + 1], M) : 0;
        be = min((int)S16[f], M);
    }
    if (t == 0) {
        unsigned kf = (unsigned)(g[c0] >> 48);
        int bf = (kf >= 32768u) ? (int)(kf - 32768u) : 0;
        int last = min(c0 + 255, M - 1);
        unsigned kl = (unsigned)(g[last] >> 48);
        int bl = (kl >= 32768u) ? (int)(kl - 32768u) : 0;
        s_rs = (bf < 32767) ? min((int)S16[bf + 1], M) : 0;
        s_re = min((int)S16[bl], M);
    }
    __syncthreads();
    int rs = s_rs, re = s_re;
    int cgt = 0;
    for (int tb = rs; tb < re; tb += RTILE) {
        int navail = min(RTILE, re - tb);
        __syncthreads();
        for (int j = t; j < navail; j += 256) tile[j] = g[tb + j];
        __syncthreads();
        if (valid) {
            int lo = max(bs, tb) - tb;
            int hi = min(be, tb + navail) - tb;
            int a0 = 0, a1 = 0, a2 = 0, a3 = 0, a4 = 0, a5 = 0, a6 = 0, a7 = 0;
            int j = lo;
            for (; j + 8 <= hi; j += 8) {
                unsigned long long v0 = tile[j + 0];
                unsigned long long v1 = tile[j + 1];
                unsigned long long v2 = tile[j + 2];
                unsigned long long v3 = tile[j + 3];
                unsigned long long v4 = tile[j + 4];
                unsigned long long v5 = tile[j + 5];
                unsigned long long v6 = tile[j + 6];
                unsigned long long v7 = tile[j + 7];
                a0 += (v0 > comp); a1 += (v1 > comp); a2 += (v2 > comp); a3 += (v3 > comp);
                a4 += (v4 > comp); a5 += (v5 > comp); a6 += (v6 > comp); a7 += (v7 > comp);
            }
            for (; j < hi; ++j) cgt += (tile[j] > comp);
            cgt += (a0 + a1 + a2 + a3) + (a4 + a5 + a6 + a7);
        }
    }
    if (!valid) return;
    int rank = bs + cgt;
    if (rank >= PRE_TOP) return;

    float4 result;
    if (ball) {
        result = pre;
    } else {
        int w = pix % W_, h = pix / W_;
        float sx = (float)(w * 16), sy = (float)(h * 16);
        result = decode_box(an0, an1, an2, an3, sx, sy, dx, dy, dw, dh, wmax, hmax);
    }
    boxes[(size_t)b * PRE_TOP + rank] = result;
}

// NMS with 128-wide groups. Wave-0 ballot walk over 2 alive flags/lane.
__global__ void __launch_bounds__(1024) nms_k(const float4* __restrict__ boxes,
                                              float* __restrict__ out) {
    __shared__ float kx1[POST_TOP], ky1[POST_TOP], kx2[POST_TOP], ky2[POST_TOP], kar[POST_TOP];
    __shared__ float gx1[GS], gy1[GS], gx2[GS], gy2[GS], gar[GS];
    __shared__ unsigned extw[4];
    __shared__ unsigned intraT[GS * 4];   // intraT[ll*4+w] bit jj => "jj suppresses ll"
    __shared__ unsigned long long s_keepA, s_keepB;
    __shared__ int s_base, s_kc, s_done;
    int b = blockIdx.x, t = threadIdx.x;
    if (t == 0) { s_kc = 0; s_done = 0; }
    const float4* bb = boxes + (size_t)b * PRE_TOP;
    const int ngroups = (PRE_TOP + GS - 1) / GS;   // 47

    float4 vcur = make_float4(0.f, 0.f, 0.f, 0.f);
    if (t < GS) vcur = bb[min(t, PRE_TOP - 1)];    // prefetch group 0

    for (int g = 0; g < ngroups; ++g) {
        __syncthreads();
        if (s_done) break;
        int gbase = g * GS;
        int gsz = min(GS, PRE_TOP - gbase);
        if (t < gsz) {
            gx1[t] = vcur.x; gy1[t] = vcur.y; gx2[t] = vcur.z; gy2[t] = vcur.w;
            gar[t] = __fmul_rn(vcur.z - vcur.x + 1.0f, vcur.w - vcur.y + 1.0f);
        }
        if (t < GS) {                              // prefetch next group under this compute
            int nidx = min(gbase + GS + t, PRE_TOP - 1);
            vcur = bb[nidx];
        }
        if (t < 4) extw[t] = 0u;
        if (t < GS * 4) intraT[t] = 0u;
        __syncthreads();

        int kc = s_kc;
        // external suppression vs kept list: 8 threads per candidate
        {
            int j = t >> 3, sub = t & 7;
            if (j < gsz) {
                float ax1 = gx1[j], ay1 = gy1[j], ax2 = gx2[j], ay2 = gy2[j], aar = gar[j];
                bool any = false;
                for (int kk = sub; kk < kc; kk += 8) {
                    if (sup_test(kx1[kk], ky1[kk], kx2[kk], ky2[kk], kar[kk],
                                 ax1, ay1, ax2, ay2, aar)) { any = true; break; }
                }
                if (any) atomicOr(&extw[j >> 5], 1u << (j & 31));
            }
        }
        // intra-group pairwise (transposed store: suppressors of ll)
        for (int p = t; p < GS * GS; p += 1024) {
            int jj = p >> 7, ll = p & (GS - 1);
            if (jj < ll && ll < gsz) {
                if (sup_test(gx1[jj], gy1[jj], gx2[jj], gy2[jj], gar[jj],
                             gx1[ll], gy1[ll], gx2[ll], gy2[ll], gar[ll])) {
                    atomicOr(&intraT[ll * 4 + (jj >> 5)], 1u << (jj & 31));
                }
            }
        }
        __syncthreads();

        // wave-0 cooperative greedy walk; lane l handles boxes l and 64+l.
        if (t < 64) {
            int l = t, lB = 64 + t;
            unsigned long long mA_lo = (unsigned long long)intraT[l * 4 + 0] |
                                       ((unsigned long long)intraT[l * 4 + 1] << 32);
            unsigned long long mB_lo = (unsigned long long)intraT[lB * 4 + 0] |
                                       ((unsigned long long)intraT[lB * 4 + 1] << 32);
            unsigned long long mB_hi = (unsigned long long)intraT[lB * 4 + 2] |
                                       ((unsigned long long)intraT[lB * 4 + 3] << 32);
            unsigned long long extA = (unsigned long long)extw[0] |
                                      ((unsigned long long)extw[1] << 32);
            unsigned long long extB = (unsigned long long)extw[2] |
                                      ((unsigned long long)extw[3] << 32);
            bool aliveA = (l < gsz) && !((extA >> l) & 1ull);
            bool aliveB = (lB < gsz) && !((extB >> l) & 1ull);
            unsigned long long keepA = 0ull, keepB = 0ull;
            int kcc = kc;
            while (kcc < POST_TOP) {
                unsigned long long am = __ballot(aliveA);
                int j;
                if (am) {
                    j = __ffsll((long long)am) - 1;
                } else {
                    unsigned long long bm = __ballot(aliveB);
                    if (!bm) break;
                    j = 64 + __ffsll((long long)bm) - 1;
                }
                if (j < 64) keepA |= (1ull << j);
                else keepB |= (1ull << (j - 64));
                ++kcc;
                if (aliveA) {
                    bool sup = (j == l) || (j < 64 && ((mA_lo >> j) & 1ull));
                    if (sup) aliveA = false;
                }
                if (aliveB) {
                    bool sup = (j == lB) ||
                               ((j < 64) ? ((mB_lo >> j) & 1ull)
                                         : ((mB_hi >> (j - 64)) & 1ull));
                    if (sup) aliveB = false;
                }
            }
            if (l == 0) {
                s_base = kc;
                s_keepA = keepA;
                s_keepB = keepB;
                s_kc = kcc;
                if (kcc >= POST_TOP) s_done = 1;
            }
        }
        __syncthreads();

        if (t < gsz) {
            bool kept = (t < 64) ? ((s_keepA >> t) & 1ull)
                                 : ((s_keepB >> (t - 64)) & 1ull);
            if (kept) {
                int rank = (t < 64)
                    ? __popcll(s_keepA & ((1ull << t) - 1ull))
                    : __popcll(s_keepA) + __popcll(s_keepB & ((1ull << (t - 64)) - 1ull));
                int slot = s_base + rank;
                kx1[slot] = gx1[t]; ky1[slot] = gy1[t];
                kx2[slot] = gx2[t]; ky2[slot] = gy2[t]; kar[slot] = gar[t];
                float* o = out + (size_t)(b * POST_TOP + slot) * 5;
                o[0] = (float)b; o[1] = gx1[t]; o[2] = gy1[t]; o[3] = gx2[t]; o[4] = gy2[t];
            }
        }
    }
    __syncthreads();
    for (int sl = s_kc + t; sl < POST_TOP; sl += 1024) {
        float* o = out + (size_t)(b * POST_TOP + sl) * 5;
        o[0] = (float)b; o[1] = 0.f; o[2] = 0.f; o[3] = 0.f; o[4] = 0.f;
    }
}

// ---------- launch ----------

extern "C" void kernel_launch(void* const* d_in, const int* in_sizes, int n_in,
                              void* d_out, int out_size, void* d_ws, size_t ws_size,
                              hipStream_t stream) {
    const float* scores  = (const float*)d_in[0];   // (8, 18, 152, 152)
    const float* deltas  = (const float*)d_in[1];   // (8, 36, 152, 152)
    const float* im_info = (const float*)d_in[2];   // (8, 3)
    const float* anchors = (const float*)d_in[3];   // (9, 4)
    float* out = (float*)d_out;                     // (8, 300, 5)

    unsigned*           hist    = (unsigned*)((char*)d_ws + OFF_HIST);
    unsigned*           cnt     = (unsigned*)((char*)d_ws + OFF_CNT);
    uint2*              cand    = (uint2*)((char*)d_ws + OFF_CAND);
    unsigned long long* grouped = (unsigned long long*)((char*)d_ws + OFF_GROUP);
    float4*             boxes   = (float4*)((char*)d_ws + OFF_BOXES);
    unsigned*           bucketT = cnt + B_ * CNT_STRIDE - 8;  // tail of cnt pad, not aliased

    bool useBall = ws_size >= WS_NEED;
    float4* ball = useBall ? (float4*)((char*)d_ws + OFF_BALL) : nullptr;

    zero2_k<<<256, 256, 0, stream>>>((unsigned*)d_ws, (unsigned*)((char*)d_ws + OFF_BOXES));
    if (useBall) {
        decode_all_k<<<dim3((HW_ + 255) / 256, B_ * A_), 256, 0, stream>>>(
            deltas, anchors, im_info, ball);
    }
    hist_k<<<dim3(64, B_), 256, 0, stream>>>(scores, hist);
    scan_k<<<B_, 1024, 0, stream>>>(hist, bucketT);
    compact_k<<<dim3(64, B_), 256, 0, stream>>>(scores, bucketT, cnt, cand);
    finesort_k<<<B_, 1024, 0, stream>>>(cnt, cand, grouped);
    rank_k<<<dim3(32, B_), 256, 0, stream>>>(cnt, grouped, (const ushort*)cand,
                                             deltas, anchors, im_info, ball, boxes);
    nms_k<<<B_, 1024, 0, stream>>>(boxes, out);
}

// Round 10
// 104.736 us; speedup vs baseline: 1.3277x; 1.3277x over previous
//
#include <hip/hip_runtime.h>
#include <stdint.h>

#define H_ 152
#define W_ 152
#define A_ 9
#define HW_ (H_ * W_)          // 23104
#define N_ (HW_ * A_)          // 207936
#define B_ 8
#define PRE_TOP 6000
#define POST_TOP 300
#define NBUCK 4096
#define NFINE 32768
#define CAND_CAP 8192
#define NMS_TH 0.7f
#define CNT_STRIDE 32          // pad per-batch counters to 128 B
#define RTILE 512

// workspace byte offsets
#define OFF_HIST    0                                   // 8*4096*4 = 131072
#define OFF_SSUF    131072                              // (unused, kept for layout)
#define OFF_CNT     262144                              // 8*32*4   = 1024
#define OFF_CAND    263168                              // 8*8192*8 = 524288  (reused as S16 u16[32768]/batch)
#define OFF_GROUP   787456                              // 8*8192*8 = 524288
#define OFF_BOXES   1311744                             // 8*6000*16= 768000
#define OFF_BALL    2079744                             // 8*207936*16 = 26615808
#define WS_NEED     (2079744ull + 26615808ull)          // 28695552

// ---------- helpers ----------

__device__ __forceinline__ unsigned fkey(float f) {
    unsigned u = __float_as_uint(f);
    return (u & 0x80000000u) ? ~u : (u | 0x80000000u);   // monotonic float->u32
}

__device__ __forceinline__ bool sup_test(float ax1, float ay1, float ax2, float ay2, float aar,
                                         float bx1, float by1, float bx2, float by2, float bar) {
    float xx1 = fmaxf(ax1, bx1);
    float yy1 = fmaxf(ay1, by1);
    float xx2 = fminf(ax2, bx2);
    float yy2 = fminf(ay2, by2);
    float iw = fmaxf(xx2 - xx1 + 1.0f, 0.0f);
    float ih = fmaxf(yy2 - yy1 + 1.0f, 0.0f);
    float inter = __fmul_rn(iw, ih);
    float iou = inter / (aar + bar - inter);
    return iou > NMS_TH;
}

// decode one box, op-order identical to reference/numpy
__device__ __forceinline__ float4 decode_box(float an0, float an1, float an2, float an3,
                                             float sx, float sy,
                                             float dx, float dy, float dw, float dh,
                                             float wmax, float hmax) {
    float ax1 = an0 + sx;
    float ay1 = an1 + sy;
    float ax2 = an2 + sx;
    float ay2 = an3 + sy;
    float ww = ax2 - ax1 + 1.0f;
    float hh = ay2 - ay1 + 1.0f;
    float ctx = ax1 + 0.5f * ww;
    float cty = ay1 + 0.5f * hh;
    float pcx = __fadd_rn(__fmul_rn(dx, ww), ctx);   // no FMA contraction (match np)
    float pcy = __fadd_rn(__fmul_rn(dy, hh), cty);
    float pw = __fmul_rn(expf(dw), ww);
    float ph = __fmul_rn(expf(dh), hh);
    float x1 = pcx - 0.5f * pw;
    float y1 = pcy - 0.5f * ph;
    float x2 = pcx + 0.5f * pw;
    float y2 = pcy + 0.5f * ph;
    x1 = fminf(fmaxf(x1, 0.0f), wmax);
    y1 = fminf(fmaxf(y1, 0.0f), hmax);
    x2 = fminf(fmaxf(x2, 0.0f), wmax);
    y2 = fminf(fmaxf(y2, 0.0f), hmax);
    return make_float4(x1, y1, x2, y2);
}

// ---------- kernels ----------

// zero two regions in one launch
__global__ void zero2_k(unsigned* __restrict__ base, unsigned* __restrict__ p2) {
    const int n1 = 263168 / 4;      // hist + (ssuf pad) + cnt
    const int n2 = 768000 / 4;      // boxes (defensive)
    int i = blockIdx.x * blockDim.x + threadIdx.x;
    int st = gridDim.x * blockDim.x;
    for (int k = i; k < n1 + n2; k += st) {
        if (k < n1) base[k] = 0u;
        else p2[k - n1] = 0u;
    }
}

// decode+clip ALL boxes, coalesced: boxesAll[b][a*HW+pix]
__global__ void decode_all_k(const float* __restrict__ deltas,
                             const float* __restrict__ anchors,
                             const float* __restrict__ im_info,
                             float4* __restrict__ ball) {
    int ba = blockIdx.y;           // 0..71
    int b = ba / A_, a = ba - (ba / A_) * A_;
    int pix = blockIdx.x * blockDim.x + threadIdx.x;
    if (pix >= HW_) return;
    const float* db = deltas + ((size_t)b * 36 + 4 * a) * HW_;
    float dx = db[pix];
    float dy = db[pix + HW_];
    float dw = db[pix + 2 * HW_];
    float dh = db[pix + 3 * HW_];
    float an0 = anchors[a * 4 + 0];
    float an1 = anchors[a * 4 + 1];
    float an2 = anchors[a * 4 + 2];
    float an3 = anchors[a * 4 + 3];
    float hmax = im_info[b * 3 + 0] - 1.0f;
    float wmax = im_info[b * 3 + 1] - 1.0f;
    int w = pix % W_, h = pix / W_;
    float sx = (float)(w * 16), sy = (float)(h * 16);
    ball[(size_t)b * N_ + a * HW_ + pix] =
        decode_box(an0, an1, an2, an3, sx, sy, dx, dy, dw, dh, wmax, hmax);
}

__global__ void hist_k(const float* __restrict__ scores, unsigned* __restrict__ hist) {
    __shared__ unsigned lh[NBUCK];
    int b = blockIdx.y;
    for (int i = threadIdx.x; i < NBUCK; i += blockDim.x) lh[i] = 0;
    __syncthreads();
    const float4* sb = (const float4*)(scores + ((size_t)b * 18 + A_) * HW_);
    const int N4 = N_ / 4;                      // 51984
    int stride = gridDim.x * blockDim.x;
    for (int e = blockIdx.x * blockDim.x + threadIdx.x; e < N4; e += stride) {
        float4 v = sb[e];
        atomicAdd(&lh[fkey(v.x) >> 20], 1u);
        atomicAdd(&lh[fkey(v.y) >> 20], 1u);
        atomicAdd(&lh[fkey(v.z) >> 20], 1u);
        atomicAdd(&lh[fkey(v.w) >> 20], 1u);
    }
    __syncthreads();
    for (int i = threadIdx.x; i < NBUCK; i += blockDim.x) {
        unsigned v = lh[i];
        if (v) atomicAdd(&hist[b * NBUCK + i], v);
    }
}

// suffix scan from top bucket; finds the coarse threshold bucket only.
__global__ void scan_k(const unsigned* __restrict__ hist, unsigned* __restrict__ bucketT) {
    __shared__ unsigned ps[1024];
    int b = blockIdx.x, t = threadIdx.x;
    const unsigned* hb = hist + b * NBUCK;
    unsigned c0 = hb[4095 - (4 * t + 0)];
    unsigned c1 = hb[4095 - (4 * t + 1)];
    unsigned c2 = hb[4095 - (4 * t + 2)];
    unsigned c3 = hb[4095 - (4 * t + 3)];
    unsigned local = c0 + c1 + c2 + c3;
    ps[t] = local;
    __syncthreads();
    for (int off = 1; off < 1024; off <<= 1) {
        unsigned v = (t >= off) ? ps[t - off] : 0u;
        __syncthreads();
        ps[t] += v;
        __syncthreads();
    }
    unsigned incl = ps[t], excl = incl - local;
    if (excl < PRE_TOP && incl >= PRE_TOP) {
        unsigned cum = excl;
        unsigned cc[4] = {c0, c1, c2, c3};
#pragma unroll
        for (int k = 0; k < 4; ++k) {
            cum += cc[k];
            if (cum >= PRE_TOP) { bucketT[b] = (unsigned)(4095 - (4 * t + k)); break; }
        }
    }
    if (t == 1023 && ps[1023] < PRE_TOP) bucketT[b] = 0;  // safety: include everything
}

__global__ void compact_k(const float* __restrict__ scores, const unsigned* __restrict__ bucketT,
                          unsigned* __restrict__ cnt, uint2* __restrict__ cand) {
    __shared__ unsigned wtot[4], wbase[4];
    __shared__ unsigned blkbase;
    int b = blockIdx.y;
    const float4* sb = (const float4*)(scores + ((size_t)b * 18 + A_) * HW_);
    unsigned T = bucketT[b];
    int lane = threadIdx.x & 63;
    int wid = threadIdx.x >> 6;
    const int N4 = N_ / 4;
    int stride = gridDim.x * blockDim.x;
    int niters = (N4 + stride - 1) / stride;
    unsigned long long lower = (lane == 63) ? 0x7fffffffffffffffull
                                            : ((1ull << lane) - 1ull);
    for (int it = 0; it < niters; ++it) {
        int e = it * stride + blockIdx.x * (int)blockDim.x + (int)threadIdx.x;
        bool p0 = false, p1 = false, p2 = false, p3 = false;
        unsigned k0 = 0, k1 = 0, k2 = 0, k3 = 0;
        if (e < N4) {
            float4 v = sb[e];
            k0 = fkey(v.x); k1 = fkey(v.y); k2 = fkey(v.z); k3 = fkey(v.w);
            p0 = (k0 >> 20) >= T; p1 = (k1 >> 20) >= T;
            p2 = (k2 >> 20) >= T; p3 = (k3 >> 20) >= T;
        }
        unsigned long long m0 = __ballot(p0), m1 = __ballot(p1);
        unsigned long long m2 = __ballot(p2), m3 = __ballot(p3);
        unsigned t0 = (unsigned)__popcll(m0), t1 = (unsigned)__popcll(m1);
        unsigned t2 = (unsigned)__popcll(m2), t3 = (unsigned)__popcll(m3);
        unsigned wtotal = t0 + t1 + t2 + t3;
        if (lane == 0) wtot[wid] = wtotal;
        __syncthreads();
        if (threadIdx.x == 0) {
            unsigned s0 = wtot[0], s1 = wtot[1], s2 = wtot[2], s3 = wtot[3];
            unsigned tot = s0 + s1 + s2 + s3;
            blkbase = tot ? atomicAdd(&cnt[b * CNT_STRIDE], tot) : 0u;
            wbase[0] = 0; wbase[1] = s0; wbase[2] = s0 + s1; wbase[3] = s0 + s1 + s2;
        }
        __syncthreads();
        if (wtotal) {
            unsigned base = blkbase + wbase[wid];
            unsigned o0 = base + (unsigned)__popcll(m0 & lower);
            unsigned o1 = base + t0 + (unsigned)__popcll(m1 & lower);
            unsigned o2 = base + t0 + t1 + (unsigned)__popcll(m2 & lower);
            unsigned o3 = base + t0 + t1 + t2 + (unsigned)__popcll(m3 & lower);
            uint2* cb = cand + (size_t)b * CAND_CAP;
            int e4 = e * 4;
            if (p0 && o0 < CAND_CAP) {
                int a = (e4 + 0) / HW_, pix = (e4 + 0) - a * HW_;
                cb[o0] = make_uint2(k0, (unsigned)(pix * A_ + a));
            }
            if (p1 && o1 < CAND_CAP) {
                int a = (e4 + 1) / HW_, pix = (e4 + 1) - a * HW_;
                cb[o1] = make_uint2(k1, (unsigned)(pix * A_ + a));
            }
            if (p2 && o2 < CAND_CAP) {
                int a = (e4 + 2) / HW_, pix = (e4 + 2) - a * HW_;
                cb[o2] = make_uint2(k2, (unsigned)(pix * A_ + a));
            }
            if (p3 && o3 < CAND_CAP) {
                int a = (e4 + 3) / HW_, pix = (e4 + 3) - a * HW_;
                cb[o3] = make_uint2(k3, (unsigned)(pix * A_ + a));
            }
        }
    }
}

// Fine (16-bit) counting sort of candidates: histogram -> suffix scan -> scatter.
// Afterwards writes per-fine-bucket END offsets (u16) over the dead cand slice.
__global__ void __launch_bounds__(1024) finesort_k(const unsigned* __restrict__ cnt,
                                                   uint2* __restrict__ cand,
                                                   unsigned long long* __restrict__ grouped) {
    __shared__ unsigned lh[NFINE];     // 128 KiB
    __shared__ unsigned ps[1024];
    int b = blockIdx.x, t = threadIdx.x;
    int M = min((int)cnt[b * CNT_STRIDE], CAND_CAP);
    uint2* cb = cand + (size_t)b * CAND_CAP;
    unsigned long long* g = grouped + (size_t)b * CAND_CAP;
    for (int i = t; i < NFINE; i += 1024) lh[i] = 0u;
    __syncthreads();
    for (int i = t; i < M; i += 1024) {
        unsigned key16 = cb[i].x >> 16;
        unsigned f = (key16 >= 32768u) ? (key16 - 32768u) : 0u;
        atomicAdd(&lh[f], 1u);
    }
    __syncthreads();
    unsigned c[32];
    unsigned local = 0;
#pragma unroll
    for (int k = 0; k < 32; ++k) { c[k] = lh[32767 - (32 * t + k)]; local += c[k]; }
    ps[t] = local;
    __syncthreads();
    for (int off = 1; off < 1024; off <<= 1) {
        unsigned v = (t >= off) ? ps[t - off] : 0u;
        __syncthreads();
        ps[t] += v;
        __syncthreads();
    }
    unsigned run = ps[t] - local;       // elements in all higher-f chunks
    __syncthreads();
#pragma unroll
    for (int k = 0; k < 32; ++k) {      // overwrite lh with S_start[f]
        lh[32767 - (32 * t + k)] = run;
        run += c[k];
    }
    __syncthreads();
    for (int i = t; i < M; i += 1024) {
        uint2 cd = cb[i];
        unsigned key16 = cd.x >> 16;
        unsigned f = (key16 >= 32768u) ? (key16 - 32768u) : 0u;
        unsigned pos = atomicAdd(&lh[f], 1u);
        if (pos < CAND_CAP)
            g[pos] = ((unsigned long long)cd.x << 32) | (unsigned)(~cd.y);
    }
    __syncthreads();
    ushort* S16 = (ushort*)cb;          // cand slice is dead; 32768*2B = 64 KiB fits exactly
    for (int i = t; i < NFINE; i += 1024)
        S16[i] = (ushort)min(lh[i], 65535u);
}

// rank candidate within its FINE bucket (count greater composites), then place its
// (pre-decoded) box into boxes[b][rank].
__global__ void __launch_bounds__(256) rank_k(const unsigned* __restrict__ cnt,
                                              const unsigned long long* __restrict__ grouped,
                                              const ushort* __restrict__ S16all,
                                              const float* __restrict__ deltas,
                                              const float* __restrict__ anchors,
                                              const float* __restrict__ im_info,
                                              const float4* __restrict__ ball,
                                              float4* __restrict__ boxes) {
    __shared__ unsigned long long tile[RTILE];
    __shared__ int s_rs, s_re;
    int b = blockIdx.y, t = threadIdx.x;
    int M = min((int)cnt[b * CNT_STRIDE], CAND_CAP);
    int c0 = blockIdx.x * 256;
    if (c0 >= M) return;
    const unsigned long long* g = grouped + (size_t)b * CAND_CAP;
    const ushort* S16 = S16all + (size_t)b * NFINE;
    int i = c0 + t;
    bool valid = i < M;
    unsigned long long comp = valid ? g[i] : 0ull;

    unsigned n = valid ? ~(unsigned)comp : 0u;
    int a = (int)(n % A_);
    int pix = (int)(n / A_);

    float4 pre = make_float4(0.f, 0.f, 0.f, 0.f);
    float dx = 0.f, dy = 0.f, dw = 0.f, dh = 0.f;
    float an0 = 0.f, an1 = 0.f, an2 = 0.f, an3 = 0.f, hmax = 0.f, wmax = 0.f;
    if (ball) {
        if (valid) pre = ball[(size_t)b * N_ + a * HW_ + pix];
    } else if (valid) {
        const float* db = deltas + (size_t)b * 36 * HW_;
        int didx = (4 * a) * HW_ + pix;
        dx = db[didx];
        dy = db[didx + HW_];
        dw = db[didx + 2 * HW_];
        dh = db[didx + 3 * HW_];
        an0 = anchors[a * 4 + 0];
        an1 = anchors[a * 4 + 1];
        an2 = anchors[a * 4 + 2];
        an3 = anchors[a * 4 + 3];
        hmax = im_info[b * 3 + 0] - 1.0f;
        wmax = im_info[b * 3 + 1] - 1.0f;
    }

    unsigned key16 = (unsigned)(comp >> 48);
    int f = (key16 >= 32768u) ? (int)(key16 - 32768u) : 0;
    int bs = 0, be = 0;
    if (valid) {
        bs = (f < 32767) ? min((int)S16[f + 1], M) : 0;
        be = min((int)S16[f], M);
    }
    if (t == 0) {
        unsigned kf = (unsigned)(g[c0] >> 48);
        int bf = (kf >= 32768u) ? (int)(kf - 32768u) : 0;
        int last = min(c0 + 255, M - 1);
        unsigned kl = (unsigned)(g[last] >> 48);
        int bl = (kl >= 32768u) ? (int)(kl - 32768u) : 0;
        s_rs = (bf < 32767) ? min((int)S16[bf + 1], M) : 0;
        s_re = min((int)S16[bl], M);
    }
    __syncthreads();
    int rs = s_rs, re = s_re;
    int cgt = 0;
    for (int tb = rs; tb < re; tb += RTILE) {
        int navail = min(RTILE, re - tb);
        __syncthreads();
        for (int j = t; j < navail; j += 256) tile[j] = g[tb + j];
        __syncthreads();
        if (valid) {
            int lo = max(bs, tb) - tb;
            int hi = min(be, tb + navail) - tb;
            int a0 = 0, a1 = 0, a2 = 0, a3 = 0, a4 = 0, a5 = 0, a6 = 0, a7 = 0;
            int j = lo;
            for (; j + 8 <= hi; j += 8) {
                unsigned long long v0 = tile[j + 0];
                unsigned long long v1 = tile[j + 1];
                unsigned long long v2 = tile[j + 2];
                unsigned long long v3 = tile[j + 3];
                unsigned long long v4 = tile[j + 4];
                unsigned long long v5 = tile[j + 5];
                unsigned long long v6 = tile[j + 6];
                unsigned long long v7 = tile[j + 7];
                a0 += (v0 > comp); a1 += (v1 > comp); a2 += (v2 > comp); a3 += (v3 > comp);
                a4 += (v4 > comp); a5 += (v5 > comp); a6 += (v6 > comp); a7 += (v7 > comp);
            }
            for (; j < hi; ++j) cgt += (tile[j] > comp);
            cgt += (a0 + a1 + a2 + a3) + (a4 + a5 + a6 + a7);
        }
    }
    if (!valid) return;
    int rank = bs + cgt;
    if (rank >= PRE_TOP) return;

    float4 result;
    if (ball) {
        result = pre;
    } else {
        int w = pix % W_, h = pix / W_;
        float sx = (float)(w * 16), sy = (float)(h * 16);
        result = decode_box(an0, an1, an2, an3, sx, sy, dx, dy, dw, dh, wmax, hmax);
    }
    boxes[(size_t)b * PRE_TOP + rank] = result;
}

// NMS, 64-wide groups, ext-gated intra phase, wave-0 ballot walk + fused append.
__global__ void __launch_bounds__(1024) nms_k(const float4* __restrict__ boxes,
                                              float* __restrict__ out) {
    __shared__ float kx1[POST_TOP], ky1[POST_TOP], kx2[POST_TOP], ky2[POST_TOP], kar[POST_TOP];
    __shared__ float gx1[64], gy1[64], gx2[64], gy2[64], gar[64];
    __shared__ unsigned extw[2];
    __shared__ unsigned intraT[128];   // intraT[ll*2+w] bit jj => "jj suppresses ll"
    __shared__ int s_kc, s_done;
    int b = blockIdx.x, t = threadIdx.x;
    if (t == 0) { s_kc = 0; s_done = 0; }
    const float4* bb = boxes + (size_t)b * PRE_TOP;
    const int ngroups = (PRE_TOP + 63) / 64;   // 94

    float4 vcur = make_float4(0.f, 0.f, 0.f, 0.f);
    if (t < 64) vcur = bb[t];                 // prefetch group 0

    for (int g = 0; g < ngroups; ++g) {
        __syncthreads();                       // prev append/kc visible
        if (s_done) break;
        int gbase = g * 64;
        int gsz = min(64, PRE_TOP - gbase);
        if (t < gsz) {
            gx1[t] = vcur.x; gy1[t] = vcur.y; gx2[t] = vcur.z; gy2[t] = vcur.w;
            gar[t] = __fmul_rn(vcur.z - vcur.x + 1.0f, vcur.w - vcur.y + 1.0f);
        }
        if (t < 64) {                          // prefetch next group under this compute
            int nidx = min(gbase + 64 + t, PRE_TOP - 1);
            vcur = bb[nidx];
        }
        if (t < 2) extw[t] = 0u;
        if (t < 128) intraT[t] = 0u;
        __syncthreads();

        int kc = s_kc;
        // ext phase: 16 threads per candidate vs kept list
        {
            int j = t >> 4, sub = t & 15;
            if (j < gsz) {
                float ax1 = gx1[j], ay1 = gy1[j], ax2 = gx2[j], ay2 = gy2[j], aar = gar[j];
                bool any = false;
                for (int kk = sub; kk < kc; kk += 16) {
                    if (sup_test(kx1[kk], ky1[kk], kx2[kk], ky2[kk], kar[kk],
                                 ax1, ay1, ax2, ay2, aar)) { any = true; break; }
                }
                if (any) atomicOr(&extw[j >> 5], 1u << (j & 31));
            }
        }
        __syncthreads();

        // alive mask (ext survivors only)
        unsigned long long ext64 = (unsigned long long)extw[0] |
                                   ((unsigned long long)extw[1] << 32);
        unsigned long long validm = (gsz >= 64) ? ~0ull : ((1ull << gsz) - 1ull);
        unsigned long long alive = (~ext64) & validm;

        // gated intra phase: only pairs where BOTH jj and ll survived ext.
        // wave w covers jj=w per iteration -> suppressed jj skips its whole wave.
        for (int p = t; p < 4096; p += 1024) {
            int jj = p >> 6, ll = p & 63;
            if (jj < ll && ((alive >> jj) & 1ull) && ((alive >> ll) & 1ull)) {
                if (sup_test(gx1[jj], gy1[jj], gx2[jj], gy2[jj], gar[jj],
                             gx1[ll], gy1[ll], gx2[ll], gy2[ll], gar[ll])) {
                    atomicOr(&intraT[ll * 2 + (jj >> 5)], 1u << (jj & 31));
                }
            }
        }
        __syncthreads();

        // wave-0: ballot walk + fused append
        if (t < 64) {
            int l = t;
            unsigned long long colm = (unsigned long long)intraT[l * 2] |
                                      ((unsigned long long)intraT[l * 2 + 1] << 32);
            bool myalive = (alive >> l) & 1ull;
            unsigned long long keep = 0ull;
            int kcc = kc;
            while (kcc < POST_TOP) {
                unsigned long long am = __ballot(myalive);
                if (!am) break;
                int j = __ffsll((long long)am) - 1;
                keep |= (1ull << j);
                ++kcc;
                if (myalive && (l == j || ((colm >> j) & 1ull))) myalive = false;
            }
            // keep is wave-uniform (built from ballots): each kept lane appends itself
            if ((keep >> l) & 1ull) {
                unsigned long long lower = (l == 63) ? 0x7fffffffffffffffull
                                                     : ((1ull << l) - 1ull);
                int rank = __popcll(keep & lower);
                int slot = kc + rank;
                kx1[slot] = gx1[l]; ky1[slot] = gy1[l];
                kx2[slot] = gx2[l]; ky2[slot] = gy2[l]; kar[slot] = gar[l];
                float* o = out + (size_t)(b * POST_TOP + slot) * 5;
                o[0] = (float)b; o[1] = gx1[l]; o[2] = gy1[l]; o[3] = gx2[l]; o[4] = gy2[l];
            }
            if (l == 0) {
                s_kc = kcc;
                if (kcc >= POST_TOP) s_done = 1;
            }
        }
    }
    __syncthreads();
    for (int sl = s_kc + t; sl < POST_TOP; sl += 1024) {
        float* o = out + (size_t)(b * POST_TOP + sl) * 5;
        o[0] = (float)b; o[1] = 0.f; o[2] = 0.f; o[3] = 0.f; o[4] = 0.f;
    }
}

// ---------- launch ----------

extern "C" void kernel_launch(void* const* d_in, const int* in_sizes, int n_in,
                              void* d_out, int out_size, void* d_ws, size_t ws_size,
                              hipStream_t stream) {
    const float* scores  = (const float*)d_in[0];   // (8, 18, 152, 152)
    const float* deltas  = (const float*)d_in[1];   // (8, 36, 152, 152)
    const float* im_info = (const float*)d_in[2];   // (8, 3)
    const float* anchors = (const float*)d_in[3];   // (9, 4)
    float* out = (float*)d_out;                     // (8, 300, 5)

    unsigned*           hist    = (unsigned*)((char*)d_ws + OFF_HIST);
    unsigned*           cnt     = (unsigned*)((char*)d_ws + OFF_CNT);
    uint2*              cand    = (uint2*)((char*)d_ws + OFF_CAND);
    unsigned long long* grouped = (unsigned long long*)((char*)d_ws + OFF_GROUP);
    float4*             boxes   = (float4*)((char*)d_ws + OFF_BOXES);
    unsigned*           bucketT = cnt + B_ * CNT_STRIDE - 8;  // tail of cnt pad, not aliased

    bool useBall = ws_size >= WS_NEED;
    float4* ball = useBall ? (float4*)((char*)d_ws + OFF_BALL) : nullptr;

    zero2_k<<<256, 256, 0, stream>>>((unsigned*)d_ws, (unsigned*)((char*)d_ws + OFF_BOXES));
    if (useBall) {
        decode_all_k<<<dim3((HW_ + 255) / 256, B_ * A_), 256, 0, stream>>>(
            deltas, anchors, im_info, ball);
    }
    hist_k<<<dim3(64, B_), 256, 0, stream>>>(scores, hist);
    scan_k<<<B_, 1024, 0, stream>>>(hist, bucketT);
    compact_k<<<dim3(64, B_), 256, 0, stream>>>(scores, bucketT, cnt, cand);
    finesort_k<<<B_, 1024, 0, stream>>>(cnt, cand, grouped);
    rank_k<<<dim3(32, B_), 256, 0, stream>>>(cnt, grouped, (const ushort*)cand,
                                             deltas, anchors, im_info, ball, boxes);
    nms_k<<<B_, 1024, 0, stream>>>(boxes, out);
}

// Round 11
// 103.505 us; speedup vs baseline: 1.3435x; 1.0119x over previous
//
#include <hip/hip_runtime.h>
#include <stdint.h>

#define H_ 152
#define W_ 152
#define A_ 9
#define HW_ (H_ * W_)          // 23104
#define N_ (HW_ * A_)          // 207936
#define B_ 8
#define PRE_TOP 6000
#define POST_TOP 300
#define NBUCK 4096
#define NFINE 32768
#define CAND_CAP 8192
#define NMS_TH 0.7f
#define CNT_STRIDE 32          // pad per-batch counters to 128 B
#define RTILE 512
#define DEC_PIXBLK 91          // ceil(23104/256)
#define DEC_BLKS (72 * DEC_PIXBLK)   // 6552
#define ZERO_BLKS 128

// workspace byte offsets
#define OFF_HIST    0                                   // 8*4096*4 = 131072
#define OFF_SSUF    131072                              // (unused, kept for layout)
#define OFF_CNT     262144                              // 8*32*4   = 1024
#define OFF_CAND    263168                              // 8*8192*8 = 524288  (reused as S16 u16[32768]/batch)
#define OFF_GROUP   787456                              // 8*8192*8 = 524288
#define OFF_BOXES   1311744                             // 8*6000*16= 768000
#define OFF_BALL    2079744                             // 8*207936*16 = 26615808
#define WS_NEED     (2079744ull + 26615808ull)          // 28695552

// ---------- helpers ----------

__device__ __forceinline__ unsigned fkey(float f) {
    unsigned u = __float_as_uint(f);
    return (u & 0x80000000u) ? ~u : (u | 0x80000000u);   // monotonic float->u32
}

__device__ __forceinline__ bool sup_test(float ax1, float ay1, float ax2, float ay2, float aar,
                                         float bx1, float by1, float bx2, float by2, float bar) {
    float xx1 = fmaxf(ax1, bx1);
    float yy1 = fmaxf(ay1, by1);
    float xx2 = fminf(ax2, bx2);
    float yy2 = fminf(ay2, by2);
    float iw = fmaxf(xx2 - xx1 + 1.0f, 0.0f);
    float ih = fmaxf(yy2 - yy1 + 1.0f, 0.0f);
    float inter = __fmul_rn(iw, ih);
    float iou = inter / (aar + bar - inter);
    return iou > NMS_TH;
}

// decode one box, op-order identical to reference/numpy
__device__ __forceinline__ float4 decode_box(float an0, float an1, float an2, float an3,
                                             float sx, float sy,
                                             float dx, float dy, float dw, float dh,
                                             float wmax, float hmax) {
    float ax1 = an0 + sx;
    float ay1 = an1 + sy;
    float ax2 = an2 + sx;
    float ay2 = an3 + sy;
    float ww = ax2 - ax1 + 1.0f;
    float hh = ay2 - ay1 + 1.0f;
    float ctx = ax1 + 0.5f * ww;
    float cty = ay1 + 0.5f * hh;
    float pcx = __fadd_rn(__fmul_rn(dx, ww), ctx);   // no FMA contraction (match np)
    float pcy = __fadd_rn(__fmul_rn(dy, hh), cty);
    float pw = __fmul_rn(expf(dw), ww);
    float ph = __fmul_rn(expf(dh), hh);
    float x1 = pcx - 0.5f * pw;
    float y1 = pcy - 0.5f * ph;
    float x2 = pcx + 0.5f * pw;
    float y2 = pcy + 0.5f * ph;
    x1 = fminf(fmaxf(x1, 0.0f), wmax);
    y1 = fminf(fmaxf(y1, 0.0f), hmax);
    x2 = fminf(fmaxf(x2, 0.0f), wmax);
    y2 = fminf(fmaxf(y2, 0.0f), hmax);
    return make_float4(x1, y1, x2, y2);
}

// ---------- kernels ----------

// fused: decode all boxes (blocks 0..DEC_BLKS-1) + zero scratch (last ZERO_BLKS blocks)
__global__ void init_k(const float* __restrict__ deltas,
                       const float* __restrict__ anchors,
                       const float* __restrict__ im_info,
                       float4* __restrict__ ball,
                       unsigned* __restrict__ zbase, unsigned* __restrict__ zboxes,
                       int nDecBlks) {
    int bid = blockIdx.x;
    if (bid < nDecBlks) {
        int ba = bid / DEC_PIXBLK;
        int b = ba / A_, a = ba - (ba / A_) * A_;
        int pix = (bid % DEC_PIXBLK) * 256 + threadIdx.x;
        if (pix >= HW_) return;
        const float* db = deltas + ((size_t)b * 36 + 4 * a) * HW_;
        float dx = db[pix];
        float dy = db[pix + HW_];
        float dw = db[pix + 2 * HW_];
        float dh = db[pix + 3 * HW_];
        float an0 = anchors[a * 4 + 0];
        float an1 = anchors[a * 4 + 1];
        float an2 = anchors[a * 4 + 2];
        float an3 = anchors[a * 4 + 3];
        float hmax = im_info[b * 3 + 0] - 1.0f;
        float wmax = im_info[b * 3 + 1] - 1.0f;
        int w = pix % W_, h = pix / W_;
        float sx = (float)(w * 16), sy = (float)(h * 16);
        ball[(size_t)b * N_ + a * HW_ + pix] =
            decode_box(an0, an1, an2, an3, sx, sy, dx, dy, dw, dh, wmax, hmax);
    } else {
        const int n1 = 263168 / 4;      // hist + (ssuf pad) + cnt
        const int n2 = 768000 / 4;      // boxes (defensive)
        int i = (bid - nDecBlks) * 256 + (int)threadIdx.x;
        int st = ZERO_BLKS * 256;
        for (int k = i; k < n1 + n2; k += st) {
            if (k < n1) zbase[k] = 0u;
            else zboxes[k - n1] = 0u;
        }
    }
}

__global__ void hist_k(const float* __restrict__ scores, unsigned* __restrict__ hist) {
    __shared__ unsigned lh[NBUCK];
    int b = blockIdx.y;
    for (int i = threadIdx.x; i < NBUCK; i += blockDim.x) lh[i] = 0;
    __syncthreads();
    const float4* sb = (const float4*)(scores + ((size_t)b * 18 + A_) * HW_);
    const int N4 = N_ / 4;                      // 51984
    int stride = gridDim.x * blockDim.x;
    for (int e = blockIdx.x * blockDim.x + threadIdx.x; e < N4; e += stride) {
        float4 v = sb[e];
        atomicAdd(&lh[fkey(v.x) >> 20], 1u);
        atomicAdd(&lh[fkey(v.y) >> 20], 1u);
        atomicAdd(&lh[fkey(v.z) >> 20], 1u);
        atomicAdd(&lh[fkey(v.w) >> 20], 1u);
    }
    __syncthreads();
    for (int i = threadIdx.x; i < NBUCK; i += blockDim.x) {
        unsigned v = lh[i];
        if (v) atomicAdd(&hist[b * NBUCK + i], v);
    }
}

// suffix scan from top bucket; finds the coarse threshold bucket only.
__global__ void scan_k(const unsigned* __restrict__ hist, unsigned* __restrict__ bucketT) {
    __shared__ unsigned ps[1024];
    int b = blockIdx.x, t = threadIdx.x;
    const unsigned* hb = hist + b * NBUCK;
    unsigned c0 = hb[4095 - (4 * t + 0)];
    unsigned c1 = hb[4095 - (4 * t + 1)];
    unsigned c2 = hb[4095 - (4 * t + 2)];
    unsigned c3 = hb[4095 - (4 * t + 3)];
    unsigned local = c0 + c1 + c2 + c3;
    ps[t] = local;
    __syncthreads();
    for (int off = 1; off < 1024; off <<= 1) {
        unsigned v = (t >= off) ? ps[t - off] : 0u;
        __syncthreads();
        ps[t] += v;
        __syncthreads();
    }
    unsigned incl = ps[t], excl = incl - local;
    if (excl < PRE_TOP && incl >= PRE_TOP) {
        unsigned cum = excl;
        unsigned cc[4] = {c0, c1, c2, c3};
#pragma unroll
        for (int k = 0; k < 4; ++k) {
            cum += cc[k];
            if (cum >= PRE_TOP) { bucketT[b] = (unsigned)(4095 - (4 * t + k)); break; }
        }
    }
    if (t == 1023 && ps[1023] < PRE_TOP) bucketT[b] = 0;  // safety: include everything
}

__global__ void compact_k(const float* __restrict__ scores, const unsigned* __restrict__ bucketT,
                          unsigned* __restrict__ cnt, uint2* __restrict__ cand) {
    __shared__ unsigned wtot[4], wbase[4];
    __shared__ unsigned blkbase;
    int b = blockIdx.y;
    const float4* sb = (const float4*)(scores + ((size_t)b * 18 + A_) * HW_);
    unsigned T = bucketT[b];
    int lane = threadIdx.x & 63;
    int wid = threadIdx.x >> 6;
    const int N4 = N_ / 4;
    int stride = gridDim.x * blockDim.x;
    int niters = (N4 + stride - 1) / stride;
    unsigned long long lower = (lane == 63) ? 0x7fffffffffffffffull
                                            : ((1ull << lane) - 1ull);
    for (int it = 0; it < niters; ++it) {
        int e = it * stride + blockIdx.x * (int)blockDim.x + (int)threadIdx.x;
        bool p0 = false, p1 = false, p2 = false, p3 = false;
        unsigned k0 = 0, k1 = 0, k2 = 0, k3 = 0;
        if (e < N4) {
            float4 v = sb[e];
            k0 = fkey(v.x); k1 = fkey(v.y); k2 = fkey(v.z); k3 = fkey(v.w);
            p0 = (k0 >> 20) >= T; p1 = (k1 >> 20) >= T;
            p2 = (k2 >> 20) >= T; p3 = (k3 >> 20) >= T;
        }
        unsigned long long m0 = __ballot(p0), m1 = __ballot(p1);
        unsigned long long m2 = __ballot(p2), m3 = __ballot(p3);
        unsigned t0 = (unsigned)__popcll(m0), t1 = (unsigned)__popcll(m1);
        unsigned t2 = (unsigned)__popcll(m2), t3 = (unsigned)__popcll(m3);
        unsigned wtotal = t0 + t1 + t2 + t3;
        if (lane == 0) wtot[wid] = wtotal;
        __syncthreads();
        if (threadIdx.x == 0) {
            unsigned s0 = wtot[0], s1 = wtot[1], s2 = wtot[2], s3 = wtot[3];
            unsigned tot = s0 + s1 + s2 + s3;
            blkbase = tot ? atomicAdd(&cnt[b * CNT_STRIDE], tot) : 0u;
            wbase[0] = 0; wbase[1] = s0; wbase[2] = s0 + s1; wbase[3] = s0 + s1 + s2;
        }
        __syncthreads();
        if (wtotal) {
            unsigned base = blkbase + wbase[wid];
            unsigned o0 = base + (unsigned)__popcll(m0 & lower);
            unsigned o1 = base + t0 + (unsigned)__popcll(m1 & lower);
            unsigned o2 = base + t0 + t1 + (unsigned)__popcll(m2 & lower);
            unsigned o3 = base + t0 + t1 + t2 + (unsigned)__popcll(m3 & lower);
            uint2* cb = cand + (size_t)b * CAND_CAP;
            int e4 = e * 4;
            if (p0 && o0 < CAND_CAP) {
                int a = (e4 + 0) / HW_, pix = (e4 + 0) - a * HW_;
                cb[o0] = make_uint2(k0, (unsigned)(pix * A_ + a));
            }
            if (p1 && o1 < CAND_CAP) {
                int a = (e4 + 1) / HW_, pix = (e4 + 1) - a * HW_;
                cb[o1] = make_uint2(k1, (unsigned)(pix * A_ + a));
            }
            if (p2 && o2 < CAND_CAP) {
                int a = (e4 + 2) / HW_, pix = (e4 + 2) - a * HW_;
                cb[o2] = make_uint2(k2, (unsigned)(pix * A_ + a));
            }
            if (p3 && o3 < CAND_CAP) {
                int a = (e4 + 3) / HW_, pix = (e4 + 3) - a * HW_;
                cb[o3] = make_uint2(k3, (unsigned)(pix * A_ + a));
            }
        }
    }
}

// Fine (16-bit) counting sort of candidates: histogram -> suffix scan -> scatter.
// Afterwards writes per-fine-bucket END offsets (u16) over the dead cand slice.
__global__ void __launch_bounds__(1024) finesort_k(const unsigned* __restrict__ cnt,
                                                   uint2* __restrict__ cand,
                                                   unsigned long long* __restrict__ grouped) {
    __shared__ unsigned lh[NFINE];     // 128 KiB
    __shared__ unsigned ps[1024];
    int b = blockIdx.x, t = threadIdx.x;
    int M = min((int)cnt[b * CNT_STRIDE], CAND_CAP);
    uint2* cb = cand + (size_t)b * CAND_CAP;
    unsigned long long* g = grouped + (size_t)b * CAND_CAP;
    for (int i = t; i < NFINE; i += 1024) lh[i] = 0u;
    __syncthreads();
    for (int i = t; i < M; i += 1024) {
        unsigned key16 = cb[i].x >> 16;
        unsigned f = (key16 >= 32768u) ? (key16 - 32768u) : 0u;
        atomicAdd(&lh[f], 1u);
    }
    __syncthreads();
    unsigned c[32];
    unsigned local = 0;
#pragma unroll
    for (int k = 0; k < 32; ++k) { c[k] = lh[32767 - (32 * t + k)]; local += c[k]; }
    ps[t] = local;
    __syncthreads();
    for (int off = 1; off < 1024; off <<= 1) {
        unsigned v = (t >= off) ? ps[t - off] : 0u;
        __syncthreads();
        ps[t] += v;
        __syncthreads();
    }
    unsigned run = ps[t] - local;       // elements in all higher-f chunks
    __syncthreads();
#pragma unroll
    for (int k = 0; k < 32; ++k) {      // overwrite lh with S_start[f]
        lh[32767 - (32 * t + k)] = run;
        run += c[k];
    }
    __syncthreads();
    for (int i = t; i < M; i += 1024) {
        uint2 cd = cb[i];
        unsigned key16 = cd.x >> 16;
        unsigned f = (key16 >= 32768u) ? (key16 - 32768u) : 0u;
        unsigned pos = atomicAdd(&lh[f], 1u);
        if (pos < CAND_CAP)
            g[pos] = ((unsigned long long)cd.x << 32) | (unsigned)(~cd.y);
    }
    __syncthreads();
    ushort* S16 = (ushort*)cb;          // cand slice is dead; 32768*2B = 64 KiB fits exactly
    for (int i = t; i < NFINE; i += 1024)
        S16[i] = (ushort)min(lh[i], 65535u);
}

// rank candidate within its FINE bucket (count greater composites), then place its
// (pre-decoded) box into boxes[b][rank].
__global__ void __launch_bounds__(256) rank_k(const unsigned* __restrict__ cnt,
                                              const unsigned long long* __restrict__ grouped,
                                              const ushort* __restrict__ S16all,
                                              const float* __restrict__ deltas,
                                              const float* __restrict__ anchors,
                                              const float* __restrict__ im_info,
                                              const float4* __restrict__ ball,
                                              float4* __restrict__ boxes) {
    __shared__ unsigned long long tile[RTILE];
    __shared__ int s_rs, s_re;
    int b = blockIdx.y, t = threadIdx.x;
    int M = min((int)cnt[b * CNT_STRIDE], CAND_CAP);
    int c0 = blockIdx.x * 256;
    if (c0 >= M) return;
    const unsigned long long* g = grouped + (size_t)b * CAND_CAP;
    const ushort* S16 = S16all + (size_t)b * NFINE;
    int i = c0 + t;
    bool valid = i < M;
    unsigned long long comp = valid ? g[i] : 0ull;

    unsigned n = valid ? ~(unsigned)comp : 0u;
    int a = (int)(n % A_);
    int pix = (int)(n / A_);

    float4 pre = make_float4(0.f, 0.f, 0.f, 0.f);
    float dx = 0.f, dy = 0.f, dw = 0.f, dh = 0.f;
    float an0 = 0.f, an1 = 0.f, an2 = 0.f, an3 = 0.f, hmax = 0.f, wmax = 0.f;
    if (ball) {
        if (valid) pre = ball[(size_t)b * N_ + a * HW_ + pix];
    } else if (valid) {
        const float* db = deltas + (size_t)b * 36 * HW_;
        int didx = (4 * a) * HW_ + pix;
        dx = db[didx];
        dy = db[didx + HW_];
        dw = db[didx + 2 * HW_];
        dh = db[didx + 3 * HW_];
        an0 = anchors[a * 4 + 0];
        an1 = anchors[a * 4 + 1];
        an2 = anchors[a * 4 + 2];
        an3 = anchors[a * 4 + 3];
        hmax = im_info[b * 3 + 0] - 1.0f;
        wmax = im_info[b * 3 + 1] - 1.0f;
    }

    unsigned key16 = (unsigned)(comp >> 48);
    int f = (key16 >= 32768u) ? (int)(key16 - 32768u) : 0;
    int bs = 0, be = 0;
    if (valid) {
        bs = (f < 32767) ? min((int)S16[f + 1], M) : 0;
        be = min((int)S16[f], M);
    }
    if (t == 0) {
        unsigned kf = (unsigned)(g[c0] >> 48);
        int bf = (kf >= 32768u) ? (int)(kf - 32768u) : 0;
        int last = min(c0 + 255, M - 1);
        unsigned kl = (unsigned)(g[last] >> 48);
        int bl = (kl >= 32768u) ? (int)(kl - 32768u) : 0;
        s_rs = (bf < 32767) ? min((int)S16[bf + 1], M) : 0;
        s_re = min((int)S16[bl], M);
    }
    __syncthreads();
    int rs = s_rs, re = s_re;
    int cgt = 0;
    for (int tb = rs; tb < re; tb += RTILE) {
        int navail = min(RTILE, re - tb);
        __syncthreads();
        for (int j = t; j < navail; j += 256) tile[j] = g[tb + j];
        __syncthreads();
        if (valid) {
            int lo = max(bs, tb) - tb;
            int hi = min(be, tb + navail) - tb;
            int a0 = 0, a1 = 0, a2 = 0, a3 = 0, a4 = 0, a5 = 0, a6 = 0, a7 = 0;
            int j = lo;
            for (; j + 8 <= hi; j += 8) {
                unsigned long long v0 = tile[j + 0];
                unsigned long long v1 = tile[j + 1];
                unsigned long long v2 = tile[j + 2];
                unsigned long long v3 = tile[j + 3];
                unsigned long long v4 = tile[j + 4];
                unsigned long long v5 = tile[j + 5];
                unsigned long long v6 = tile[j + 6];
                unsigned long long v7 = tile[j + 7];
                a0 += (v0 > comp); a1 += (v1 > comp); a2 += (v2 > comp); a3 += (v3 > comp);
                a4 += (v4 > comp); a5 += (v5 > comp); a6 += (v6 > comp); a7 += (v7 > comp);
            }
            for (; j < hi; ++j) cgt += (tile[j] > comp);
            cgt += (a0 + a1 + a2 + a3) + (a4 + a5 + a6 + a7);
        }
    }
    if (!valid) return;
    int rank = bs + cgt;
    if (rank >= PRE_TOP) return;

    float4 result;
    if (ball) {
        result = pre;
    } else {
        int w = pix % W_, h = pix / W_;
        float sx = (float)(w * 16), sy = (float)(h * 16);
        result = decode_box(an0, an1, an2, an3, sx, sy, dx, dy, dw, dh, wmax, hmax);
    }
    boxes[(size_t)b * PRE_TOP + rank] = result;
}

// NMS: 64-wide groups, 3 barriers/group, register-resident candidate boxes,
// ext (waves 0-11) and intra (waves 12-15) run concurrently.
__global__ void __launch_bounds__(1024) nms_k(const float4* __restrict__ boxes,
                                              float* __restrict__ out) {
    __shared__ float kx1[POST_TOP], ky1[POST_TOP], kx2[POST_TOP], ky2[POST_TOP], kar[POST_TOP];
    __shared__ unsigned extw[2];
    __shared__ unsigned intraw[128];   // intraw[l*2+w] bit j => "j suppresses l"
    __shared__ int s_kc, s_done;
    int b = blockIdx.x, t = threadIdx.x;
    int lane = t & 63, w = t >> 6;     // 16 waves
    if (t == 0) { s_kc = 0; s_done = 0; }
    const float4* bb = boxes + (size_t)b * PRE_TOP;
    const int ngroups = (PRE_TOP + 63) / 64;   // 94

    // every thread holds ITS LANE's candidate of the current group in registers
    float4 vcur = bb[lane];            // group 0 (L1-broadcast across waves)

    for (int g = 0; g < ngroups; ++g) {
        __syncthreads();                // top: prev append + s_kc visible; masks free
        if (s_done) break;
        int gbase = g * 64;
        int gsz = min(64, PRE_TOP - gbase);
        if (t < 2) extw[t] = 0u;
        if (t < 128) intraw[t] = 0u;
        float ar = __fmul_rn(vcur.z - vcur.x + 1.0f, vcur.w - vcur.y + 1.0f);
        __syncthreads();                // masks zeroed, kept list stable
        int kc = s_kc;

        if (w < 12) {
            // ext: lane's candidate vs kept list, stride 12 across ext waves,
            // kept box reads are wave-uniform LDS broadcasts; unroll-2 pairs.
            bool sup = false;
            if (lane < gsz) {
                for (int kk = w; kk < kc && !sup; kk += 24) {
                    int k2i = kk + 12;
                    bool s0 = sup_test(kx1[kk], ky1[kk], kx2[kk], ky2[kk], kar[kk],
                                       vcur.x, vcur.y, vcur.z, vcur.w, ar);
                    bool s1 = false;
                    if (k2i < kc)
                        s1 = sup_test(kx1[k2i], ky1[k2i], kx2[k2i], ky2[k2i], kar[k2i],
                                      vcur.x, vcur.y, vcur.z, vcur.w, ar);
                    sup = s0 || s1;
                }
            }
            unsigned long long m = __ballot(sup);
            if (lane == 0 && (unsigned)m) atomicOr(&extw[0], (unsigned)m);
            if (lane == 0 && (unsigned)(m >> 32)) atomicOr(&extw[1], (unsigned)(m >> 32));
        } else {
            // intra: lane = ll; jj = (w-12) + 4*it, wave-uniform -> shfl broadcast
            int wi = w - 12;
            unsigned long long colm = 0ull;
            for (int jj = wi; jj < 64; jj += 4) {
                float bx1 = __shfl(vcur.x, jj);
                float by1 = __shfl(vcur.y, jj);
                float bx2 = __shfl(vcur.z, jj);
                float by2 = __shfl(vcur.w, jj);
                float bar = __shfl(ar, jj);
                if (jj < lane && lane < gsz && jj < gsz &&
                    sup_test(bx1, by1, bx2, by2, bar,
                             vcur.x, vcur.y, vcur.z, vcur.w, ar)) {
                    colm |= (1ull << jj);
                }
            }
            if ((unsigned)colm) atomicOr(&intraw[lane * 2], (unsigned)colm);
            if ((unsigned)(colm >> 32)) atomicOr(&intraw[lane * 2 + 1], (unsigned)(colm >> 32));
        }
        __syncthreads();                // masks complete

        // wave-0: ballot walk + fused append (boxes from registers)
        if (w == 0) {
            unsigned long long colm = (unsigned long long)intraw[lane * 2] |
                                      ((unsigned long long)intraw[lane * 2 + 1] << 32);
            unsigned long long ext64 = (unsigned long long)extw[0] |
                                       ((unsigned long long)extw[1] << 32);
            bool alive = (lane < gsz) && !((ext64 >> lane) & 1ull);
            unsigned long long keep = 0ull;
            int kcc = kc;
            while (kcc < POST_TOP) {
                unsigned long long am = __ballot(alive);
                if (!am) break;
                int j = __ffsll((long long)am) - 1;
                keep |= (1ull << j);
                ++kcc;
                if (alive && (lane == j || ((colm >> j) & 1ull))) alive = false;
            }
            if ((keep >> lane) & 1ull) {
                unsigned long long lower = (lane == 63) ? 0x7fffffffffffffffull
                                                        : ((1ull << lane) - 1ull);
                int rank = __popcll(keep & lower);
                int slot = kc + rank;
                kx1[slot] = vcur.x; ky1[slot] = vcur.y;
                kx2[slot] = vcur.z; ky2[slot] = vcur.w; kar[slot] = ar;
                float* o = out + (size_t)(b * POST_TOP + slot) * 5;
                o[0] = (float)b; o[1] = vcur.x; o[2] = vcur.y; o[3] = vcur.z; o[4] = vcur.w;
            }
            if (lane == 0) {
                s_kc = kcc;
                if (kcc >= POST_TOP) s_done = 1;
            }
        }
        // prefetch next group's lane box (after walk used vcur)
        vcur = bb[min(gbase + 64 + lane, PRE_TOP - 1)];
    }
    __syncthreads();
    for (int sl = s_kc + t; sl < POST_TOP; sl += 1024) {
        float* o = out + (size_t)(b * POST_TOP + sl) * 5;
        o[0] = (float)b; o[1] = 0.f; o[2] = 0.f; o[3] = 0.f; o[4] = 0.f;
    }
}

// ---------- launch ----------

extern "C" void kernel_launch(void* const* d_in, const int* in_sizes, int n_in,
                              void* d_out, int out_size, void* d_ws, size_t ws_size,
                              hipStream_t stream) {
    const float* scores  = (const float*)d_in[0];   // (8, 18, 152, 152)
    const float* deltas  = (const float*)d_in[1];   // (8, 36, 152, 152)
    const float* im_info = (const float*)d_in[2];   // (8, 3)
    const float* anchors = (const float*)d_in[3];   // (9, 4)
    float* out = (float*)d_out;                     // (8, 300, 5)

    unsigned*           hist    = (unsigned*)((char*)d_ws + OFF_HIST);
    unsigned*           cnt     = (unsigned*)((char*)d_ws + OFF_CNT);
    uint2*              cand    = (uint2*)((char*)d_ws + OFF_CAND);
    unsigned long long* grouped = (unsigned long long*)((char*)d_ws + OFF_GROUP);
    float4*             boxes   = (float4*)((char*)d_ws + OFF_BOXES);
    unsigned*           bucketT = cnt + B_ * CNT_STRIDE - 8;  // tail of cnt pad, not aliased

    bool useBall = ws_size >= WS_NEED;
    float4* ball = useBall ? (float4*)((char*)d_ws + OFF_BALL) : nullptr;

    int nDec = useBall ? DEC_BLKS : 0;
    init_k<<<nDec + ZERO_BLKS, 256, 0, stream>>>(deltas, anchors, im_info, ball,
                                                 (unsigned*)d_ws,
                                                 (unsigned*)((char*)d_ws + OFF_BOXES), nDec);
    hist_k<<<dim3(64, B_), 256, 0, stream>>>(scores, hist);
    scan_k<<<B_, 1024, 0, stream>>>(hist, bucketT);
    compact_k<<<dim3(64, B_), 256, 0, stream>>>(scores, bucketT, cnt, cand);
    finesort_k<<<B_, 1024, 0, stream>>>(cnt, cand, grouped);
    rank_k<<<dim3(32, B_), 256, 0, stream>>>(cnt, grouped, (const ushort*)cand,
                                             deltas, anchors, im_info, ball, boxes);
    nms_k<<<B_, 1024, 0, stream>>>(boxes, out);
}

// Round 12
// 93.594 us; speedup vs baseline: 1.4857x; 1.1059x over previous
//
#include <hip/hip_runtime.h>
#include <stdint.h>

#define H_ 152
#define W_ 152
#define A_ 9
#define HW_ (H_ * W_)          // 23104
#define N_ (HW_ * A_)          // 207936
#define B_ 8
#define PRE_TOP 6000
#define POST_TOP 300
#define NBUCK 4096
#define NFINE 32768
#define CAND_CAP 8192
#define NMS_TH 0.7f
#define CNT_STRIDE 32          // pad per-batch counters to 128 B
#define RTILE 512
#define DEC_PIXBLK 91          // ceil(23104/256)
#define DEC_BLKS (72 * DEC_PIXBLK)   // 6552
#define ZERO_BLKS 128

// workspace byte offsets
#define OFF_HIST    0                                   // 8*4096*4 = 131072
#define OFF_SSUF    131072                              // (unused, kept for layout)
#define OFF_CNT     262144                              // 8*32*4   = 1024
#define OFF_CAND    263168                              // 8*8192*8 = 524288  (reused as S16 u16[32768]/batch)
#define OFF_GROUP   787456                              // 8*8192*8 = 524288
#define OFF_BOXES   1311744                             // 8*6000*16= 768000
#define OFF_BALL    2079744                             // 8*207936*16 = 26615808
#define WS_NEED     (2079744ull + 26615808ull)          // 28695552

// ---------- helpers ----------

__device__ __forceinline__ unsigned fkey(float f) {
    unsigned u = __float_as_uint(f);
    return (u & 0x80000000u) ? ~u : (u | 0x80000000u);   // monotonic float->u32
}

__device__ __forceinline__ bool sup_test(float ax1, float ay1, float ax2, float ay2, float aar,
                                         float bx1, float by1, float bx2, float by2, float bar) {
    float xx1 = fmaxf(ax1, bx1);
    float yy1 = fmaxf(ay1, by1);
    float xx2 = fminf(ax2, bx2);
    float yy2 = fminf(ay2, by2);
    float iw = fmaxf(xx2 - xx1 + 1.0f, 0.0f);
    float ih = fmaxf(yy2 - yy1 + 1.0f, 0.0f);
    float inter = __fmul_rn(iw, ih);
    float iou = inter / (aar + bar - inter);
    return iou > NMS_TH;
}

// decode one box, op-order identical to reference/numpy
__device__ __forceinline__ float4 decode_box(float an0, float an1, float an2, float an3,
                                             float sx, float sy,
                                             float dx, float dy, float dw, float dh,
                                             float wmax, float hmax) {
    float ax1 = an0 + sx;
    float ay1 = an1 + sy;
    float ax2 = an2 + sx;
    float ay2 = an3 + sy;
    float ww = ax2 - ax1 + 1.0f;
    float hh = ay2 - ay1 + 1.0f;
    float ctx = ax1 + 0.5f * ww;
    float cty = ay1 + 0.5f * hh;
    float pcx = __fadd_rn(__fmul_rn(dx, ww), ctx);   // no FMA contraction (match np)
    float pcy = __fadd_rn(__fmul_rn(dy, hh), cty);
    float pw = __fmul_rn(expf(dw), ww);
    float ph = __fmul_rn(expf(dh), hh);
    float x1 = pcx - 0.5f * pw;
    float y1 = pcy - 0.5f * ph;
    float x2 = pcx + 0.5f * pw;
    float y2 = pcy + 0.5f * ph;
    x1 = fminf(fmaxf(x1, 0.0f), wmax);
    y1 = fminf(fmaxf(y1, 0.0f), hmax);
    x2 = fminf(fmaxf(x2, 0.0f), wmax);
    y2 = fminf(fmaxf(y2, 0.0f), hmax);
    return make_float4(x1, y1, x2, y2);
}

// ---------- kernels ----------

// fused: decode all boxes (blocks 0..DEC_BLKS-1) + zero scratch (last ZERO_BLKS blocks)
__global__ void init_k(const float* __restrict__ deltas,
                       const float* __restrict__ anchors,
                       const float* __restrict__ im_info,
                       float4* __restrict__ ball,
                       unsigned* __restrict__ zbase, unsigned* __restrict__ zboxes,
                       int nDecBlks) {
    int bid = blockIdx.x;
    if (bid < nDecBlks) {
        int ba = bid / DEC_PIXBLK;
        int b = ba / A_, a = ba - (ba / A_) * A_;
        int pix = (bid % DEC_PIXBLK) * 256 + threadIdx.x;
        if (pix >= HW_) return;
        const float* db = deltas + ((size_t)b * 36 + 4 * a) * HW_;
        float dx = db[pix];
        float dy = db[pix + HW_];
        float dw = db[pix + 2 * HW_];
        float dh = db[pix + 3 * HW_];
        float an0 = anchors[a * 4 + 0];
        float an1 = anchors[a * 4 + 1];
        float an2 = anchors[a * 4 + 2];
        float an3 = anchors[a * 4 + 3];
        float hmax = im_info[b * 3 + 0] - 1.0f;
        float wmax = im_info[b * 3 + 1] - 1.0f;
        int w = pix % W_, h = pix / W_;
        float sx = (float)(w * 16), sy = (float)(h * 16);
        ball[(size_t)b * N_ + a * HW_ + pix] =
            decode_box(an0, an1, an2, an3, sx, sy, dx, dy, dw, dh, wmax, hmax);
    } else {
        const int n1 = 263168 / 4;      // hist + (ssuf pad) + cnt
        const int n2 = 768000 / 4;      // boxes (defensive)
        int i = (bid - nDecBlks) * 256 + (int)threadIdx.x;
        int st = ZERO_BLKS * 256;
        for (int k = i; k < n1 + n2; k += st) {
            if (k < n1) zbase[k] = 0u;
            else zboxes[k - n1] = 0u;
        }
    }
}

__global__ void hist_k(const float* __restrict__ scores, unsigned* __restrict__ hist) {
    __shared__ unsigned lh[NBUCK];
    int b = blockIdx.y;
    for (int i = threadIdx.x; i < NBUCK; i += blockDim.x) lh[i] = 0;
    __syncthreads();
    const float4* sb = (const float4*)(scores + ((size_t)b * 18 + A_) * HW_);
    const int N4 = N_ / 4;                      // 51984
    int stride = gridDim.x * blockDim.x;
    for (int e = blockIdx.x * blockDim.x + threadIdx.x; e < N4; e += stride) {
        float4 v = sb[e];
        atomicAdd(&lh[fkey(v.x) >> 20], 1u);
        atomicAdd(&lh[fkey(v.y) >> 20], 1u);
        atomicAdd(&lh[fkey(v.z) >> 20], 1u);
        atomicAdd(&lh[fkey(v.w) >> 20], 1u);
    }
    __syncthreads();
    for (int i = threadIdx.x; i < NBUCK; i += blockDim.x) {
        unsigned v = lh[i];
        if (v) atomicAdd(&hist[b * NBUCK + i], v);
    }
}

// suffix scan from top bucket; finds the coarse threshold bucket only.
__global__ void scan_k(const unsigned* __restrict__ hist, unsigned* __restrict__ bucketT) {
    __shared__ unsigned ps[1024];
    int b = blockIdx.x, t = threadIdx.x;
    const unsigned* hb = hist + b * NBUCK;
    unsigned c0 = hb[4095 - (4 * t + 0)];
    unsigned c1 = hb[4095 - (4 * t + 1)];
    unsigned c2 = hb[4095 - (4 * t + 2)];
    unsigned c3 = hb[4095 - (4 * t + 3)];
    unsigned local = c0 + c1 + c2 + c3;
    ps[t] = local;
    __syncthreads();
    for (int off = 1; off < 1024; off <<= 1) {
        unsigned v = (t >= off) ? ps[t - off] : 0u;
        __syncthreads();
        ps[t] += v;
        __syncthreads();
    }
    unsigned incl = ps[t], excl = incl - local;
    if (excl < PRE_TOP && incl >= PRE_TOP) {
        unsigned cum = excl;
        unsigned cc[4] = {c0, c1, c2, c3};
#pragma unroll
        for (int k = 0; k < 4; ++k) {
            cum += cc[k];
            if (cum >= PRE_TOP) { bucketT[b] = (unsigned)(4095 - (4 * t + k)); break; }
        }
    }
    if (t == 1023 && ps[1023] < PRE_TOP) bucketT[b] = 0;  // safety: include everything
}

__global__ void compact_k(const float* __restrict__ scores, const unsigned* __restrict__ bucketT,
                          unsigned* __restrict__ cnt, uint2* __restrict__ cand) {
    __shared__ unsigned wtot[4], wbase[4];
    __shared__ unsigned blkbase;
    int b = blockIdx.y;
    const float4* sb = (const float4*)(scores + ((size_t)b * 18 + A_) * HW_);
    unsigned T = bucketT[b];
    int lane = threadIdx.x & 63;
    int wid = threadIdx.x >> 6;
    const int N4 = N_ / 4;
    int stride = gridDim.x * blockDim.x;
    int niters = (N4 + stride - 1) / stride;
    unsigned long long lower = (lane == 63) ? 0x7fffffffffffffffull
                                            : ((1ull << lane) - 1ull);
    for (int it = 0; it < niters; ++it) {
        int e = it * stride + blockIdx.x * (int)blockDim.x + (int)threadIdx.x;
        bool p0 = false, p1 = false, p2 = false, p3 = false;
        unsigned k0 = 0, k1 = 0, k2 = 0, k3 = 0;
        if (e < N4) {
            float4 v = sb[e];
            k0 = fkey(v.x); k1 = fkey(v.y); k2 = fkey(v.z); k3 = fkey(v.w);
            p0 = (k0 >> 20) >= T; p1 = (k1 >> 20) >= T;
            p2 = (k2 >> 20) >= T; p3 = (k3 >> 20) >= T;
        }
        unsigned long long m0 = __ballot(p0), m1 = __ballot(p1);
        unsigned long long m2 = __ballot(p2), m3 = __ballot(p3);
        unsigned t0 = (unsigned)__popcll(m0), t1 = (unsigned)__popcll(m1);
        unsigned t2 = (unsigned)__popcll(m2), t3 = (unsigned)__popcll(m3);
        unsigned wtotal = t0 + t1 + t2 + t3;
        if (lane == 0) wtot[wid] = wtotal;
        __syncthreads();
        if (threadIdx.x == 0) {
            unsigned s0 = wtot[0], s1 = wtot[1], s2 = wtot[2], s3 = wtot[3];
            unsigned tot = s0 + s1 + s2 + s3;
            blkbase = tot ? atomicAdd(&cnt[b * CNT_STRIDE], tot) : 0u;
            wbase[0] = 0; wbase[1] = s0; wbase[2] = s0 + s1; wbase[3] = s0 + s1 + s2;
        }
        __syncthreads();
        if (wtotal) {
            unsigned base = blkbase + wbase[wid];
            unsigned o0 = base + (unsigned)__popcll(m0 & lower);
            unsigned o1 = base + t0 + (unsigned)__popcll(m1 & lower);
            unsigned o2 = base + t0 + t1 + (unsigned)__popcll(m2 & lower);
            unsigned o3 = base + t0 + t1 + t2 + (unsigned)__popcll(m3 & lower);
            uint2* cb = cand + (size_t)b * CAND_CAP;
            int e4 = e * 4;
            if (p0 && o0 < CAND_CAP) {
                int a = (e4 + 0) / HW_, pix = (e4 + 0) - a * HW_;
                cb[o0] = make_uint2(k0, (unsigned)(pix * A_ + a));
            }
            if (p1 && o1 < CAND_CAP) {
                int a = (e4 + 1) / HW_, pix = (e4 + 1) - a * HW_;
                cb[o1] = make_uint2(k1, (unsigned)(pix * A_ + a));
            }
            if (p2 && o2 < CAND_CAP) {
                int a = (e4 + 2) / HW_, pix = (e4 + 2) - a * HW_;
                cb[o2] = make_uint2(k2, (unsigned)(pix * A_ + a));
            }
            if (p3 && o3 < CAND_CAP) {
                int a = (e4 + 3) / HW_, pix = (e4 + 3) - a * HW_;
                cb[o3] = make_uint2(k3, (unsigned)(pix * A_ + a));
            }
        }
    }
}

// Fine (16-bit) counting sort of candidates: histogram -> suffix scan -> scatter.
// Afterwards writes per-fine-bucket END offsets (u16) over the dead cand slice.
__global__ void __launch_bounds__(1024) finesort_k(const unsigned* __restrict__ cnt,
                                                   uint2* __restrict__ cand,
                                                   unsigned long long* __restrict__ grouped) {
    __shared__ unsigned lh[NFINE];     // 128 KiB
    __shared__ unsigned ps[1024];
    int b = blockIdx.x, t = threadIdx.x;
    int M = min((int)cnt[b * CNT_STRIDE], CAND_CAP);
    uint2* cb = cand + (size_t)b * CAND_CAP;
    unsigned long long* g = grouped + (size_t)b * CAND_CAP;
    for (int i = t; i < NFINE; i += 1024) lh[i] = 0u;
    __syncthreads();
    for (int i = t; i < M; i += 1024) {
        unsigned key16 = cb[i].x >> 16;
        unsigned f = (key16 >= 32768u) ? (key16 - 32768u) : 0u;
        atomicAdd(&lh[f], 1u);
    }
    __syncthreads();
    unsigned c[32];
    unsigned local = 0;
#pragma unroll
    for (int k = 0; k < 32; ++k) { c[k] = lh[32767 - (32 * t + k)]; local += c[k]; }
    ps[t] = local;
    __syncthreads();
    for (int off = 1; off < 1024; off <<= 1) {
        unsigned v = (t >= off) ? ps[t - off] : 0u;
        __syncthreads();
        ps[t] += v;
        __syncthreads();
    }
    unsigned run = ps[t] - local;       // elements in all higher-f chunks
    __syncthreads();
#pragma unroll
    for (int k = 0; k < 32; ++k) {      // overwrite lh with S_start[f]
        lh[32767 - (32 * t + k)] = run;
        run += c[k];
    }
    __syncthreads();
    for (int i = t; i < M; i += 1024) {
        uint2 cd = cb[i];
        unsigned key16 = cd.x >> 16;
        unsigned f = (key16 >= 32768u) ? (key16 - 32768u) : 0u;
        unsigned pos = atomicAdd(&lh[f], 1u);
        if (pos < CAND_CAP)
            g[pos] = ((unsigned long long)cd.x << 32) | (unsigned)(~cd.y);
    }
    __syncthreads();
    ushort* S16 = (ushort*)cb;          // cand slice is dead; 32768*2B = 64 KiB fits exactly
    for (int i = t; i < NFINE; i += 1024)
        S16[i] = (ushort)min(lh[i], 65535u);
}

// rank candidate within its FINE bucket (count greater composites), then place its
// (pre-decoded) box into boxes[b][rank].
__global__ void __launch_bounds__(256) rank_k(const unsigned* __restrict__ cnt,
                                              const unsigned long long* __restrict__ grouped,
                                              const ushort* __restrict__ S16all,
                                              const float* __restrict__ deltas,
                                              const float* __restrict__ anchors,
                                              const float* __restrict__ im_info,
                                              const float4* __restrict__ ball,
                                              float4* __restrict__ boxes) {
    __shared__ unsigned long long tile[RTILE];
    __shared__ int s_rs, s_re;
    int b = blockIdx.y, t = threadIdx.x;
    int M = min((int)cnt[b * CNT_STRIDE], CAND_CAP);
    int c0 = blockIdx.x * 256;
    if (c0 >= M) return;
    const unsigned long long* g = grouped + (size_t)b * CAND_CAP;
    const ushort* S16 = S16all + (size_t)b * NFINE;
    int i = c0 + t;
    bool valid = i < M;
    unsigned long long comp = valid ? g[i] : 0ull;

    unsigned n = valid ? ~(unsigned)comp : 0u;
    int a = (int)(n % A_);
    int pix = (int)(n / A_);

    float4 pre = make_float4(0.f, 0.f, 0.f, 0.f);
    float dx = 0.f, dy = 0.f, dw = 0.f, dh = 0.f;
    float an0 = 0.f, an1 = 0.f, an2 = 0.f, an3 = 0.f, hmax = 0.f, wmax = 0.f;
    if (ball) {
        if (valid) pre = ball[(size_t)b * N_ + a * HW_ + pix];
    } else if (valid) {
        const float* db = deltas + (size_t)b * 36 * HW_;
        int didx = (4 * a) * HW_ + pix;
        dx = db[didx];
        dy = db[didx + HW_];
        dw = db[didx + 2 * HW_];
        dh = db[didx + 3 * HW_];
        an0 = anchors[a * 4 + 0];
        an1 = anchors[a * 4 + 1];
        an2 = anchors[a * 4 + 2];
        an3 = anchors[a * 4 + 3];
        hmax = im_info[b * 3 + 0] - 1.0f;
        wmax = im_info[b * 3 + 1] - 1.0f;
    }

    unsigned key16 = (unsigned)(comp >> 48);
    int f = (key16 >= 32768u) ? (int)(key16 - 32768u) : 0;
    int bs = 0, be = 0;
    if (valid) {
        bs = (f < 32767) ? min((int)S16[f + 1], M) : 0;
        be = min((int)S16[f], M);
    }
    if (t == 0) {
        unsigned kf = (unsigned)(g[c0] >> 48);
        int bf = (kf >= 32768u) ? (int)(kf - 32768u) : 0;
        int last = min(c0 + 255, M - 1);
        unsigned kl = (unsigned)(g[last] >> 48);
        int bl = (kl >= 32768u) ? (int)(kl - 32768u) : 0;
        s_rs = (bf < 32767) ? min((int)S16[bf + 1], M) : 0;
        s_re = min((int)S16[bl], M);
    }
    __syncthreads();
    int rs = s_rs, re = s_re;
    int cgt = 0;
    for (int tb = rs; tb < re; tb += RTILE) {
        int navail = min(RTILE, re - tb);
        __syncthreads();
        for (int j = t; j < navail; j += 256) tile[j] = g[tb + j];
        __syncthreads();
        if (valid) {
            int lo = max(bs, tb) - tb;
            int hi = min(be, tb + navail) - tb;
            int a0 = 0, a1 = 0, a2 = 0, a3 = 0, a4 = 0, a5 = 0, a6 = 0, a7 = 0;
            int j = lo;
            for (; j + 8 <= hi; j += 8) {
                unsigned long long v0 = tile[j + 0];
                unsigned long long v1 = tile[j + 1];
                unsigned long long v2 = tile[j + 2];
                unsigned long long v3 = tile[j + 3];
                unsigned long long v4 = tile[j + 4];
                unsigned long long v5 = tile[j + 5];
                unsigned long long v6 = tile[j + 6];
                unsigned long long v7 = tile[j + 7];
                a0 += (v0 > comp); a1 += (v1 > comp); a2 += (v2 > comp); a3 += (v3 > comp);
                a4 += (v4 > comp); a5 += (v5 > comp); a6 += (v6 > comp); a7 += (v7 > comp);
            }
            for (; j < hi; ++j) cgt += (tile[j] > comp);
            cgt += (a0 + a1 + a2 + a3) + (a4 + a5 + a6 + a7);
        }
    }
    if (!valid) return;
    int rank = bs + cgt;
    if (rank >= PRE_TOP) return;

    float4 result;
    if (ball) {
        result = pre;
    } else {
        int w = pix % W_, h = pix / W_;
        float sx = (float)(w * 16), sy = (float)(h * 16);
        result = decode_box(an0, an1, an2, an3, sx, sy, dx, dy, dw, dh, wmax, hmax);
    }
    boxes[(size_t)b * PRE_TOP + rank] = result;
}

// NMS: proven R6 skeleton (4 barriers, t0-serial walk, append phase) with
// float4-packed LDS, hoisted lane-own box, ballot-aggregated intra atomics.
__global__ void __launch_bounds__(1024) nms_k(const float4* __restrict__ boxes,
                                              float* __restrict__ out) {
    __shared__ float4 kbox[POST_TOP];
    __shared__ float  karea[POST_TOP];
    __shared__ float4 gbox4[64];
    __shared__ float  gar[64];
    __shared__ unsigned extw[2];
    __shared__ unsigned intraw[128];   // row jj: bits ll that jj suppresses
    __shared__ unsigned long long s_keep;
    __shared__ int s_base, s_kc, s_done;
    int b = blockIdx.x, t = threadIdx.x;
    int lane = t & 63, w = t >> 6;
    if (t == 0) { s_kc = 0; s_done = 0; }
    const float4* bb = boxes + (size_t)b * PRE_TOP;
    const int ngroups = (PRE_TOP + 63) / 64;   // 94

    float4 vcur = make_float4(0.f, 0.f, 0.f, 0.f);
    if (t < 64) vcur = bb[t];                 // prefetch group 0

    for (int g = 0; g < ngroups; ++g) {
        __syncthreads();                       // prev append + s_kc visible
        if (s_done) break;
        int gbase = g * 64;
        int gsz = min(64, PRE_TOP - gbase);
        if (t < gsz) {
            gbox4[t] = vcur;
            gar[t] = __fmul_rn(vcur.z - vcur.x + 1.0f, vcur.w - vcur.y + 1.0f);
        }
        if (t < 64) {                          // prefetch next group under this compute
            int nidx = min(gbase + 64 + t, PRE_TOP - 1);
            vcur = bb[nidx];
        }
        if (t < 2) extw[t] = 0u;
        if (t < 128) intraw[t] = 0u;
        __syncthreads();

        int kc = s_kc;
        // ext phase: 16 threads per candidate vs kept list (packed reads: 2 LDS/iter)
        {
            int j = t >> 4, sub = t & 15;
            if (j < gsz) {
                float4 cb4 = gbox4[j];          // 16-lane broadcast
                float car = gar[j];
                bool any = false;
                for (int kk = sub; kk < kc && !any; kk += 16) {
                    float4 kb = kbox[kk];
                    float ka = karea[kk];
                    any = sup_test(kb.x, kb.y, kb.z, kb.w, ka,
                                   cb4.x, cb4.y, cb4.z, cb4.w, car);
                }
                if (any) atomicOr(&extw[j >> 5], 1u << (j & 31));
            }
        }
        // intra phase: lane = ll (own box in regs, read once); wave w covers
        // jj in {w, w+16, w+32, w+48} (wave-uniform -> broadcast reads);
        // ballot-aggregated mask write (2 atomics per wave-iter).
        {
            float4 mb = gbox4[lane];            // stride-1 b128, conflict-free
            float mar = gar[lane];
#pragma unroll
            for (int it = 0; it < 4; ++it) {
                int jj = w + it * 16;
                float4 bj = gbox4[jj];          // wave-uniform broadcast
                float baj = gar[jj];
                bool sup = (jj < lane) && (lane < gsz) && (jj < gsz) &&
                           sup_test(bj.x, bj.y, bj.z, bj.w, baj,
                                    mb.x, mb.y, mb.z, mb.w, mar);
                unsigned long long m = __ballot(sup);
                if (lane == 0 && (unsigned)m) atomicOr(&intraw[2 * jj], (unsigned)m);
                if (lane == 1 && (unsigned)(m >> 32))
                    atomicOr(&intraw[2 * jj + 1], (unsigned)(m >> 32));
            }
        }
        __syncthreads();

        if (t == 0) {
            unsigned long long ext64 = (unsigned long long)extw[0] |
                                       ((unsigned long long)extw[1] << 32);
            unsigned long long validm = (gsz >= 64) ? ~0ull : ((1ull << gsz) - 1ull);
            unsigned long long alive = (~ext64) & validm;
            unsigned long long keep = 0ull;
            int kcc = s_kc;
            s_base = kcc;
            while (alive && kcc < POST_TOP) {
                int j = __ffsll((long long)alive) - 1;
                keep |= (1ull << j);
                ++kcc;
                unsigned long long row = (unsigned long long)intraw[2 * j] |
                                         ((unsigned long long)intraw[2 * j + 1] << 32);
                alive &= ~row;
                alive &= ~(1ull << j);
            }
            s_keep = keep;
            s_kc = kcc;
            if (kcc >= POST_TOP) s_done = 1;
        }
        __syncthreads();

        if (t < gsz && ((s_keep >> t) & 1ull)) {
            int rank = __popcll(s_keep & ((1ull << t) - 1ull));
            int slot = s_base + rank;
            float4 mb = gbox4[t];
            kbox[slot] = mb;
            karea[slot] = gar[t];
            float* o = out + (size_t)(b * POST_TOP + slot) * 5;
            o[0] = (float)b; o[1] = mb.x; o[2] = mb.y; o[3] = mb.z; o[4] = mb.w;
        }
    }
    __syncthreads();
    for (int sl = s_kc + t; sl < POST_TOP; sl += 1024) {
        float* o = out + (size_t)(b * POST_TOP + sl) * 5;
        o[0] = (float)b; o[1] = 0.f; o[2] = 0.f; o[3] = 0.f; o[4] = 0.f;
    }
}

// ---------- launch ----------

extern "C" void kernel_launch(void* const* d_in, const int* in_sizes, int n_in,
                              void* d_out, int out_size, void* d_ws, size_t ws_size,
                              hipStream_t stream) {
    const float* scores  = (const float*)d_in[0];   // (8, 18, 152, 152)
    const float* deltas  = (const float*)d_in[1];   // (8, 36, 152, 152)
    const float* im_info = (const float*)d_in[2];   // (8, 3)
    const float* anchors = (const float*)d_in[3];   // (9, 4)
    float* out = (float*)d_out;                     // (8, 300, 5)

    unsigned*           hist    = (unsigned*)((char*)d_ws + OFF_HIST);
    unsigned*           cnt     = (unsigned*)((char*)d_ws + OFF_CNT);
    uint2*              cand    = (uint2*)((char*)d_ws + OFF_CAND);
    unsigned long long* grouped = (unsigned long long*)((char*)d_ws + OFF_GROUP);
    float4*             boxes   = (float4*)((char*)d_ws + OFF_BOXES);
    unsigned*           bucketT = cnt + B_ * CNT_STRIDE - 8;  // tail of cnt pad, not aliased

    bool useBall = ws_size >= WS_NEED;
    float4* ball = useBall ? (float4*)((char*)d_ws + OFF_BALL) : nullptr;

    int nDec = useBall ? DEC_BLKS : 0;
    init_k<<<nDec + ZERO_BLKS, 256, 0, stream>>>(deltas, anchors, im_info, ball,
                                                 (unsigned*)d_ws,
                                                 (unsigned*)((char*)d_ws + OFF_BOXES), nDec);
    hist_k<<<dim3(64, B_), 256, 0, stream>>>(scores, hist);
    scan_k<<<B_, 1024, 0, stream>>>(hist, bucketT);
    compact_k<<<dim3(64, B_), 256, 0, stream>>>(scores, bucketT, cnt, cand);
    finesort_k<<<B_, 1024, 0, stream>>>(cnt, cand, grouped);
    rank_k<<<dim3(32, B_), 256, 0, stream>>>(cnt, grouped, (const ushort*)cand,
                                             deltas, anchors, im_info, ball, boxes);
    nms_k<<<B_, 1024, 0, stream>>>(boxes, out);
}